// Round 3
// baseline (150.450 us; speedup 1.0000x reference)
//
#include <hip/hip_runtime.h>
#include <hip/hip_bf16.h>

// Problem constants: B=8, NUM=4 -> BB=32 batches; LQ=128, LP=512, H=512.
#define BBATCH 32
#define LQ 128
#define LP 512
#define HDIM 512
#define GDIM 2560   // 5*H concat width
#define NEG_MAX (-3.402823466e38f)

typedef __attribute__((ext_vector_type(8))) short short8;
typedef __attribute__((ext_vector_type(4))) float f32x4;
typedef __attribute__((ext_vector_type(4))) unsigned short ushort4v;

__device__ inline unsigned short f2bf(float f) {
  union { float f; unsigned int u; } v; v.f = f;
  unsigned int r = v.u + 0x7FFFu + ((v.u >> 16) & 1u);  // RNE
  return (unsigned short)(r >> 16);
}
__device__ inline float bf2f(unsigned short s) {
  union { unsigned int u; float f; } v; v.u = (unsigned int)s << 16;
  return v.f;
}

// ---------------- cast: f32 [R][512] -> bf16 normal + transposed (+ optional wm-scaled) ----------------
// Also fused: bias dot  biasOut[b,row] += sum_h src[row,h]*wbias[h]  (atomicAdd, pre-zeroed).
template <int R, bool W>
__global__ __launch_bounds__(256) void cast_kernel(
    const float* __restrict__ src, const float* __restrict__ wbias,
    const float* __restrict__ wscale,
    unsigned short* __restrict__ dstN, unsigned short* __restrict__ dstT,
    unsigned short* __restrict__ dstW, float* __restrict__ biasOut) {
  int b = blockIdx.z;
  int p0 = blockIdx.y * 64, h0 = blockIdx.x * 64;
  src += (long)b * R * HDIM;
  dstN += (long)b * R * HDIM;
  dstT += (long)b * HDIM * R;
  __shared__ float T[64][65];
  int t = threadIdx.x;
  int c4 = (t & 15) * 4, r = t >> 4;
  float4 wb = *(const float4*)(wbias + h0 + c4);
  float4 wsc = {0, 0, 0, 0};
  if (W) wsc = *(const float4*)(wscale + h0 + c4);
#pragma unroll
  for (int i = 0; i < 4; i++) {
    int row = r + 16 * i;
    float4 v = *(const float4*)(src + (long)(p0 + row) * HDIM + h0 + c4);
    T[row][c4] = v.x; T[row][c4 + 1] = v.y; T[row][c4 + 2] = v.z; T[row][c4 + 3] = v.w;
    ushort4v o = {f2bf(v.x), f2bf(v.y), f2bf(v.z), f2bf(v.w)};
    *(ushort4v*)(dstN + (long)(p0 + row) * HDIM + h0 + c4) = o;
    if (W) {
      ushort4v ow = {f2bf(v.x * wsc.x), f2bf(v.y * wsc.y), f2bf(v.z * wsc.z), f2bf(v.w * wsc.w)};
      *(ushort4v*)(dstW + (long)b * R * HDIM + (long)(p0 + row) * HDIM + h0 + c4) = ow;
    }
    float dot = v.x * wb.x + v.y * wb.y + v.z * wb.z + v.w * wb.w;
#pragma unroll
    for (int s = 1; s < 16; s <<= 1) dot += __shfl_xor(dot, s);
    if ((t & 15) == 0) atomicAdd(biasOut + b * R + p0 + row, dot);
  }
  __syncthreads();
#pragma unroll
  for (int i = 0; i < 4; i++) {
    int hh = r + 16 * i;
    ushort4v o = {f2bf(T[c4][hh]), f2bf(T[c4 + 1][hh]), f2bf(T[c4 + 2][hh]), f2bf(T[c4 + 3][hh])};
    *(ushort4v*)(dstT + (long)(h0 + hh) * R + p0 + c4) = o;
  }
}

// ---------------- MFMA NT GEMM: A [M][K] bf16, B [N][K] bf16, lda=ldb=K, 128x128 tile ----------------
// EPI=0: U epilogue: fused row-softmax(acc+eq, mask) -> Apb [p][q] + ApT [q][p] bf16;
//        UmT [q][p] f32 = masked(acc+ep) for later col-softmax. Requires N==128, grid.x==1.
// EPI=1: out chunks {0:E, 1:v, 3:E*v} * maskM, E from bf16 Esrc; optional Tout bf16 [n][m].
// EPI=2: out chunks {2:v, 4:E*v} * maskM.
// EPI=3: plain bf16 C [M][N] -> Tout.
template <int EPI>
__global__ __launch_bounds__(256) void mfma_gemm(
    const unsigned short* __restrict__ Ab, const unsigned short* __restrict__ Bb,
    int M, int N, int K,
    const float* __restrict__ epv, const float* __restrict__ eqv,
    const int* __restrict__ maskM, const int* __restrict__ maskN,
    float* __restrict__ UmT, unsigned short* __restrict__ Apb,
    unsigned short* __restrict__ ApT,
    float* __restrict__ outBase, const unsigned short* __restrict__ Esrc,
    unsigned short* __restrict__ Tout) {
  const int b = blockIdx.z;
  const unsigned short* A = Ab + (long)b * M * K;
  const unsigned short* B = Bb + (long)b * N * K;
  const int m0 = blockIdx.y * 128, n0 = blockIdx.x * 128;
  __shared__ unsigned short As[8192];  // [128 rows][64 k] bf16, XOR-swizzled
  __shared__ unsigned short Bs[8192];
  const int t = threadIdx.x, lane = t & 63, wid = t >> 6;
  const int wr = (wid >> 1) * 64, wc = (wid & 1) * 64;
  const int fr = lane & 15, fq = lane >> 4;
  f32x4 acc[4][4] = {};
  for (int k0 = 0; k0 < K; k0 += 64) {
#pragma unroll
    for (int i = 0; i < 4; i++) {
      int o = (t + i * 256) * 16;
      int row = o >> 7, col = (o & 127) >> 1;
      int swz = o ^ ((row & 7) << 4);
      *(short8*)((char*)As + swz) = *(const short8*)(A + (long)(m0 + row) * K + k0 + col);
      *(short8*)((char*)Bs + swz) = *(const short8*)(B + (long)(n0 + row) * K + k0 + col);
    }
    __syncthreads();
#pragma unroll
    for (int ks = 0; ks < 2; ks++) {
      short8 af[4], bfv[4];
#pragma unroll
      for (int i = 0; i < 4; i++) {
        int rowA = wr + i * 16 + fr;
        af[i] = *(const short8*)((const char*)As + (((rowA << 7) + ks * 64 + fq * 16) ^ ((rowA & 7) << 4)));
        int rowB = wc + i * 16 + fr;
        bfv[i] = *(const short8*)((const char*)Bs + (((rowB << 7) + ks * 64 + fq * 16) ^ ((rowB & 7) << 4)));
      }
#pragma unroll
      for (int i = 0; i < 4; i++)
#pragma unroll
        for (int j = 0; j < 4; j++)
          acc[i][j] = __builtin_amdgcn_mfma_f32_16x16x32_bf16(af[i], bfv[j], acc[i][j], 0, 0, 0);
    }
    __syncthreads();
  }
  // ---- epilogues ----
  if (EPI == 0) {
    __shared__ float smax[2][128], ssum[2][128];
    const float* ep_b = epv + (long)b * M;
    const float* eq_b = eqv + (long)b * N;
    const int* mM = maskM + (long)b * M;
    const int* mN = maskN + (long)b * N;
    float* UmTB = UmT + (long)b * M * N;          // [q][p]
    unsigned short* ApB = Apb + (long)b * M * N;  // [p][q]
    unsigned short* ApTB = ApT + (long)b * M * N; // [q][p]
    float eqc[4]; int mnc[4];
#pragma unroll
    for (int j = 0; j < 4; j++) {
      int col = wc + j * 16 + fr;
      eqc[j] = eq_b[col]; mnc[j] = mN[col];
    }
    float epr[4][4]; int mmr[4][4];
#pragma unroll
    for (int i = 0; i < 4; i++)
#pragma unroll
      for (int r = 0; r < 4; r++) {
        int row = m0 + wr + i * 16 + fq * 4 + r;
        epr[i][r] = ep_b[row]; mmr[i][r] = mM[row];
      }
    // UmT = masked(acc+ep); acc <- masked(acc+eq) for row-softmax
#pragma unroll
    for (int i = 0; i < 4; i++)
#pragma unroll
      for (int j = 0; j < 4; j++) {
        int col = wc + j * 16 + fr;
        float4 tv;
#pragma unroll
        for (int r = 0; r < 4; r++) {
          float a = acc[i][j][r];
          bool ok = mmr[i][r] && mnc[j];
          ((float*)&tv)[r] = ok ? a + epr[i][r] : NEG_MAX;
          acc[i][j][r] = ok ? a + eqc[j] : NEG_MAX;
        }
        *(float4*)(UmTB + (long)col * M + m0 + wr + i * 16 + fq * 4) = tv;
      }
    // row max: over j in-reg, over fr via shfl, across 2 column-waves via LDS
    float mx[4][4];
#pragma unroll
    for (int i = 0; i < 4; i++)
#pragma unroll
      for (int r = 0; r < 4; r++) {
        float m = fmaxf(fmaxf(acc[i][0][r], acc[i][1][r]), fmaxf(acc[i][2][r], acc[i][3][r]));
#pragma unroll
        for (int s = 1; s < 16; s <<= 1) m = fmaxf(m, __shfl_xor(m, s));
        mx[i][r] = m;
        if (fr == 0) smax[wid & 1][wr + i * 16 + fq * 4 + r] = m;
      }
    __syncthreads();
#pragma unroll
    for (int i = 0; i < 4; i++)
#pragma unroll
      for (int r = 0; r < 4; r++) {
        int rl = wr + i * 16 + fq * 4 + r;
        mx[i][r] = fmaxf(smax[0][rl], smax[1][rl]);
      }
    // exp & sum
#pragma unroll
    for (int i = 0; i < 4; i++)
#pragma unroll
      for (int r = 0; r < 4; r++) {
        float s = 0.f;
#pragma unroll
        for (int j = 0; j < 4; j++) {
          float e = __expf(acc[i][j][r] - mx[i][r]);
          acc[i][j][r] = e; s += e;
        }
#pragma unroll
        for (int sh = 1; sh < 16; sh <<= 1) s += __shfl_xor(s, sh);
        if (fr == 0) ssum[wid & 1][wr + i * 16 + fq * 4 + r] = s;
      }
    __syncthreads();
    float inv[4][4];
#pragma unroll
    for (int i = 0; i < 4; i++)
#pragma unroll
      for (int r = 0; r < 4; r++) {
        int rl = wr + i * 16 + fq * 4 + r;
        float S = ssum[0][rl] + ssum[1][rl];
        inv[i][r] = S > 0.f ? 1.f / S : 0.f;
      }
    // write Apb (scalar u16) + ApT (ushort4)
#pragma unroll
    for (int i = 0; i < 4; i++)
#pragma unroll
      for (int j = 0; j < 4; j++) {
        int col = wc + j * 16 + fr;
        int row0 = m0 + wr + i * 16 + fq * 4;
        ushort4v o;
#pragma unroll
        for (int r = 0; r < 4; r++) {
          bool ok = mmr[i][r] && mnc[j];
          float val = ok ? acc[i][j][r] * inv[i][r] : 0.f;
          o[r] = f2bf(val);
          ApB[(long)(row0 + r) * N + col] = o[r];
        }
        *(ushort4v*)(ApTB + (long)col * M + row0) = o;
      }
  } else if (EPI == 1 || EPI == 2) {
    float* outB = outBase + (long)b * M * GDIM;
    const unsigned short* EB = Esrc + (long)b * M * HDIM;
    const int* mM = maskM + (long)b * M;
    unsigned short* ToutB = Tout ? Tout + (long)b * N * M : nullptr;
#pragma unroll
    for (int i = 0; i < 4; i++) {
#pragma unroll
      for (int r = 0; r < 4; r++) {
        int row = m0 + wr + i * 16 + fq * 4 + r;
        float mm = (float)mM[row];
        float* orow = outB + (long)row * GDIM;
        const unsigned short* erow = EB + (long)row * HDIM;
#pragma unroll
        for (int j = 0; j < 4; j++) {
          int col = n0 + wc + j * 16 + fr;
          float v = acc[i][j][r];
          float e = bf2f(erow[col]);
          if (EPI == 1) {
            orow[col] = e * mm;
            orow[HDIM + col] = v * mm;
            orow[3 * HDIM + col] = e * v * mm;
          } else {
            orow[2 * HDIM + col] = v * mm;
            orow[4 * HDIM + col] = e * v * mm;
          }
        }
      }
      if (EPI == 1 && Tout) {
#pragma unroll
        for (int j = 0; j < 4; j++) {
          int col = n0 + wc + j * 16 + fr;
          int row0 = m0 + wr + i * 16 + fq * 4;
          ushort4v o = {f2bf(acc[i][j][0]), f2bf(acc[i][j][1]),
                        f2bf(acc[i][j][2]), f2bf(acc[i][j][3])};
          *(ushort4v*)(ToutB + (long)col * M + row0) = o;
        }
      }
    }
  } else {  // EPI == 3: plain bf16 C
    unsigned short* CB = Tout + (long)b * M * N;
#pragma unroll
    for (int i = 0; i < 4; i++)
#pragma unroll
      for (int j = 0; j < 4; j++) {
        int col = n0 + wc + j * 16 + fr;
#pragma unroll
        for (int r = 0; r < 4; r++)
          CB[(long)(m0 + wr + i * 16 + fq * 4 + r) * N + col] = f2bf(acc[i][j][r]);
      }
  }
}

// ---------------- col softmax over p (len 512) on UmT rows, wave per row -> BpT bf16 ----------------
__global__ __launch_bounds__(256) void colsoftmaxT_kernel(
    const float* __restrict__ UmT, unsigned short* __restrict__ BpT,
    const int* __restrict__ mp, const int* __restrict__ mq) {
  int wid = blockIdx.x * 4 + (threadIdx.x >> 6);  // = b*LQ + q
  int lane = threadIdx.x & 63;
  int b = wid >> 7;
  const float* row = UmT + (long)wid * LP;
  float v[8];
  float m = NEG_MAX;
#pragma unroll
  for (int i = 0; i < 8; i++) { v[i] = row[lane + 64 * i]; m = fmaxf(m, v[i]); }
#pragma unroll
  for (int off = 32; off; off >>= 1) m = fmaxf(m, __shfl_xor(m, off));
  float e[8];
  float s = 0.f;
#pragma unroll
  for (int i = 0; i < 8; i++) { e[i] = __expf(v[i] - m); s += e[i]; }
#pragma unroll
  for (int off = 32; off; off >>= 1) s += __shfl_xor(s, off);
  float inv = s > 0.f ? 1.f / s : 0.f;
  int mqv = mq[wid];
#pragma unroll
  for (int i = 0; i < 8; i++) {
    int p = lane + 64 * i;
    bool ok = mqv && mp[b * LP + p];
    BpT[(long)wid * LP + p] = ok ? f2bf(e[i] * inv) : 0;
  }
}

extern "C" void kernel_launch(void* const* d_in, const int* in_sizes, int n_in,
                              void* d_out, int out_size, void* d_ws, size_t ws_size,
                              hipStream_t stream) {
  const float* Eq = (const float*)d_in[0];   // (32,128,512)
  const float* Ep = (const float*)d_in[1];   // (32,512,512)
  const int* mq = (const int*)d_in[2];       // (32,128)
  const int* mp = (const int*)d_in[3];       // (32,512)
  const float* w = (const float*)d_in[4];    // (1536,)
  float* out = (float*)d_out;
  float* out_gpq = out;                                  // (32,128,2560)
  float* out_gqp = out + (long)BBATCH * LQ * GDIM;       // (32,512,2560)

  unsigned short* Epb = (unsigned short*)d_ws;  // [32][512p][512h] raw bf16
  unsigned short* EpT = Epb + 32L * 512 * 512;  // [32][512h][512p]
  unsigned short* Eqb = EpT + 32L * 512 * 512;  // [32][128q][512h]
  unsigned short* EqT = Eqb + 32L * 128 * 512;  // [32][512h][128q]
  unsigned short* Eqw = EqT + 32L * 128 * 512;  // [32][128q][512h] * wm
  unsigned short* Apb = Eqw + 32L * 128 * 512;  // [32][512p][128q]
  unsigned short* ApT = Apb + 32L * 512 * 128;  // [32][128q][512p]
  unsigned short* BpT = ApT + 32L * 512 * 128;  // [32][128q][512p]
  unsigned short* B1T = BpT + 32L * 128 * 512;  // [32][512h][128q]
  unsigned short* M2  = B1T + 32L * 512 * 128;  // [32][128q][128q']
  float* UmT = (float*)(M2 + 32L * 128 * 128);  // [32][128q][512p]
  float* epb = UmT + 32L * 128 * 512;           // [32][512]
  float* eqb2 = epb + 32L * 512;                // [32][128]

  // 0. zero bias accumulators (atomics target)
  hipMemsetAsync(epb, 0, (32L * 512 + 32L * 128) * sizeof(float), stream);

  // 1. casts + fused bias dots
  cast_kernel<512, false><<<dim3(8, 8, BBATCH), 256, 0, stream>>>(
      Ep, w + HDIM, nullptr, Epb, EpT, nullptr, epb);
  cast_kernel<128, true><<<dim3(8, 2, BBATCH), 256, 0, stream>>>(
      Eq, w, w + 2 * HDIM, Eqb, EqT, Eqw, eqb2);

  // 2. U GEMM + fused row-softmax: -> Apb, ApT, UmT
  mfma_gemm<0><<<dim3(1, 4, BBATCH), 256, 0, stream>>>(
      Epb, Eqw, LP, LQ, HDIM, epb, eqb2, mp, mq, UmT, Apb, ApT,
      nullptr, nullptr, nullptr);

  // 3. col softmax -> BpT
  colsoftmaxT_kernel<<<BBATCH * LQ / 4, 256, 0, stream>>>(UmT, BpT, mp, mq);

  // 4. M2 = Bp^T @ Ap  (128x128, K=512) -> bf16
  mfma_gemm<3><<<dim3(1, 1, BBATCH), 256, 0, stream>>>(
      BpT, ApT, LQ, LQ, LP, nullptr, nullptr, nullptr, nullptr,
      nullptr, nullptr, nullptr, nullptr, nullptr, M2);

  // 5. B2 = M2 @ Eq -> gpq chunks {2, 4}
  mfma_gemm<2><<<dim3(4, 1, BBATCH), 256, 0, stream>>>(
      M2, EqT, LQ, HDIM, LQ, nullptr, nullptr, mq, nullptr,
      nullptr, nullptr, nullptr, out_gpq, Eqb, nullptr);

  // 6. A1 = Ap @ Eq -> gqp chunks {0:E, 1:A1, 3:E*A1}
  mfma_gemm<1><<<dim3(4, 4, BBATCH), 256, 0, stream>>>(
      Apb, EqT, LP, HDIM, LQ, nullptr, nullptr, mp, nullptr,
      nullptr, nullptr, nullptr, out_gqp, Epb, nullptr);

  // 7. B1 = Bp^T @ Ep -> gpq chunks {0:E, 1:B1, 3:E*B1} + B1T
  mfma_gemm<1><<<dim3(4, 1, BBATCH), 256, 0, stream>>>(
      BpT, EpT, LQ, HDIM, LP, nullptr, nullptr, mq, nullptr,
      nullptr, nullptr, nullptr, out_gpq, Eqb, B1T);

  // 8. A2 = Ap @ B1 -> gqp chunks {2:A2, 4:E*A2}
  mfma_gemm<2><<<dim3(4, 4, BBATCH), 256, 0, stream>>>(
      Apb, B1T, LP, HDIM, LQ, nullptr, nullptr, mp, nullptr,
      nullptr, nullptr, nullptr, out_gqp, Epb, nullptr);
}

// Round 4
// 139.665 us; speedup vs baseline: 1.0772x; 1.0772x over previous
//
#include <hip/hip_runtime.h>
#include <hip/hip_bf16.h>

// Problem constants: B=8, NUM=4 -> BB=32 batches; LQ=128, LP=512, H=512.
#define BBATCH 32
#define LQ 128
#define LP 512
#define HDIM 512
#define GDIM 2560   // 5*H concat width
#define NEG_MAX (-3.402823466e38f)

typedef __attribute__((ext_vector_type(8))) short short8;
typedef __attribute__((ext_vector_type(4))) float f32x4;
typedef __attribute__((ext_vector_type(4))) unsigned short ushort4v;

__device__ inline unsigned short f2bf(float f) {
  union { float f; unsigned int u; } v; v.f = f;
  unsigned int r = v.u + 0x7FFFu + ((v.u >> 16) & 1u);  // RNE
  return (unsigned short)(r >> 16);
}
__device__ inline float bf2f(unsigned short s) {
  union { unsigned int u; float f; } v; v.u = (unsigned int)s << 16;
  return v.f;
}

// ---- shared staging / fragment helpers (128 rows x 64 k bf16 tile, XOR-swizzled) ----
__device__ inline void stage128x64(const unsigned short* __restrict__ src, int ld,
                                   int row0, int k0, unsigned short* lds, int t) {
#pragma unroll
  for (int i = 0; i < 4; i++) {
    int o = (t + i * 256) * 16;
    int row = o >> 7, col = (o & 127) >> 1;
    int swz = o ^ ((row & 7) << 4);
    *(short8*)((char*)lds + swz) = *(const short8*)(src + (long)(row0 + row) * ld + k0 + col);
  }
}
__device__ inline short8 fragld(const unsigned short* lds, int row, int ks, int fq) {
  return *(const short8*)((const char*)lds + (((row << 7) + ks * 64 + fq * 16) ^ ((row & 7) << 4)));
}

// ---------------- cast: f32 [R][512] -> bf16 normal + transposed (+ optional wm-scaled) ----------------
// Also fused: bias dot  biasOut[b,row] += sum_h src[row,h]*wbias[h]  (atomicAdd, pre-zeroed).
template <int R, bool W>
__global__ __launch_bounds__(256) void cast_kernel(
    const float* __restrict__ src, const float* __restrict__ wbias,
    const float* __restrict__ wscale,
    unsigned short* __restrict__ dstN, unsigned short* __restrict__ dstT,
    unsigned short* __restrict__ dstW, float* __restrict__ biasOut) {
  int b = blockIdx.z;
  int p0 = blockIdx.y * 64, h0 = blockIdx.x * 64;
  src += (long)b * R * HDIM;
  dstN += (long)b * R * HDIM;
  dstT += (long)b * HDIM * R;
  __shared__ float T[64][65];
  int t = threadIdx.x;
  int c4 = (t & 15) * 4, r = t >> 4;
  float4 wb = *(const float4*)(wbias + h0 + c4);
  float4 wsc = {0, 0, 0, 0};
  if (W) wsc = *(const float4*)(wscale + h0 + c4);
#pragma unroll
  for (int i = 0; i < 4; i++) {
    int row = r + 16 * i;
    float4 v = *(const float4*)(src + (long)(p0 + row) * HDIM + h0 + c4);
    T[row][c4] = v.x; T[row][c4 + 1] = v.y; T[row][c4 + 2] = v.z; T[row][c4 + 3] = v.w;
    ushort4v o = {f2bf(v.x), f2bf(v.y), f2bf(v.z), f2bf(v.w)};
    *(ushort4v*)(dstN + (long)(p0 + row) * HDIM + h0 + c4) = o;
    if (W) {
      ushort4v ow = {f2bf(v.x * wsc.x), f2bf(v.y * wsc.y), f2bf(v.z * wsc.z), f2bf(v.w * wsc.w)};
      *(ushort4v*)(dstW + (long)b * R * HDIM + (long)(p0 + row) * HDIM + h0 + c4) = ow;
    }
    float dot = v.x * wb.x + v.y * wb.y + v.z * wb.z + v.w * wb.w;
#pragma unroll
    for (int s = 1; s < 16; s <<= 1) dot += __shfl_xor(dot, s);
    if ((t & 15) == 0) atomicAdd(biasOut + b * R + p0 + row, dot);
  }
  __syncthreads();
#pragma unroll
  for (int i = 0; i < 4; i++) {
    int hh = r + 16 * i;
    ushort4v o = {f2bf(T[c4][hh]), f2bf(T[c4 + 1][hh]), f2bf(T[c4 + 2][hh]), f2bf(T[c4 + 3][hh])};
    *(ushort4v*)(dstT + (long)(h0 + hh) * R + p0 + c4) = o;
  }
}

// ---------------- MFMA NT GEMM (U + M2 only) ----------------
// EPI=0: U epilogue: fused row-softmax(acc+eq, mask) -> Apb [p][q] + ApT [q][p] bf16;
//        UmT [q][p] f32 = masked(acc+ep). Requires N==128, grid.x==1.
// EPI=3: plain bf16 C [M][N] -> Tout.
template <int EPI>
__global__ __launch_bounds__(256) void mfma_gemm(
    const unsigned short* __restrict__ Ab, const unsigned short* __restrict__ Bb,
    int M, int N, int K,
    const float* __restrict__ epv, const float* __restrict__ eqv,
    const int* __restrict__ maskM, const int* __restrict__ maskN,
    float* __restrict__ UmT, unsigned short* __restrict__ Apb,
    unsigned short* __restrict__ ApT, unsigned short* __restrict__ Tout) {
  const int b = blockIdx.z;
  const unsigned short* A = Ab + (long)b * M * K;
  const unsigned short* B = Bb + (long)b * N * K;
  const int m0 = blockIdx.y * 128, n0 = blockIdx.x * 128;
  __shared__ unsigned short As[8192];
  __shared__ unsigned short Bs[8192];
  const int t = threadIdx.x, lane = t & 63, wid = t >> 6;
  const int wr = (wid >> 1) * 64, wc = (wid & 1) * 64;
  const int fr = lane & 15, fq = lane >> 4;
  f32x4 acc[4][4] = {};
  for (int k0 = 0; k0 < K; k0 += 64) {
    stage128x64(A, K, m0, k0, As, t);
    stage128x64(B, K, n0, k0, Bs, t);
    __syncthreads();
#pragma unroll
    for (int ks = 0; ks < 2; ks++) {
      short8 af[4], bfv[4];
#pragma unroll
      for (int i = 0; i < 4; i++) {
        af[i] = fragld(As, wr + i * 16 + fr, ks, fq);
        bfv[i] = fragld(Bs, wc + i * 16 + fr, ks, fq);
      }
#pragma unroll
      for (int i = 0; i < 4; i++)
#pragma unroll
        for (int j = 0; j < 4; j++)
          acc[i][j] = __builtin_amdgcn_mfma_f32_16x16x32_bf16(af[i], bfv[j], acc[i][j], 0, 0, 0);
    }
    __syncthreads();
  }
  if (EPI == 0) {
    __shared__ float smax[2][128], ssum[2][128];
    const float* ep_b = epv + (long)b * M;
    const float* eq_b = eqv + (long)b * N;
    const int* mM = maskM + (long)b * M;
    const int* mN = maskN + (long)b * N;
    float* UmTB = UmT + (long)b * M * N;
    unsigned short* ApB = Apb + (long)b * M * N;
    unsigned short* ApTB = ApT + (long)b * M * N;
    float eqc[4]; int mnc[4];
#pragma unroll
    for (int j = 0; j < 4; j++) {
      int col = wc + j * 16 + fr;
      eqc[j] = eq_b[col]; mnc[j] = mN[col];
    }
    float epr[4][4]; int mmr[4][4];
#pragma unroll
    for (int i = 0; i < 4; i++)
#pragma unroll
      for (int r = 0; r < 4; r++) {
        int row = m0 + wr + i * 16 + fq * 4 + r;
        epr[i][r] = ep_b[row]; mmr[i][r] = mM[row];
      }
#pragma unroll
    for (int i = 0; i < 4; i++)
#pragma unroll
      for (int j = 0; j < 4; j++) {
        float4 tv;
#pragma unroll
        for (int r = 0; r < 4; r++) {
          float a = acc[i][j][r];
          bool ok = mmr[i][r] && mnc[j];
          ((float*)&tv)[r] = ok ? a + epr[i][r] : NEG_MAX;
          acc[i][j][r] = ok ? a + eqc[j] : NEG_MAX;
        }
        int col = wc + j * 16 + fr;
        *(float4*)(UmTB + (long)col * M + m0 + wr + i * 16 + fq * 4) = tv;
      }
    float mx[4][4];
#pragma unroll
    for (int i = 0; i < 4; i++)
#pragma unroll
      for (int r = 0; r < 4; r++) {
        float m = fmaxf(fmaxf(acc[i][0][r], acc[i][1][r]), fmaxf(acc[i][2][r], acc[i][3][r]));
#pragma unroll
        for (int s = 1; s < 16; s <<= 1) m = fmaxf(m, __shfl_xor(m, s));
        mx[i][r] = m;
        if (fr == 0) smax[wid & 1][wr + i * 16 + fq * 4 + r] = m;
      }
    __syncthreads();
#pragma unroll
    for (int i = 0; i < 4; i++)
#pragma unroll
      for (int r = 0; r < 4; r++) {
        int rl = wr + i * 16 + fq * 4 + r;
        mx[i][r] = fmaxf(smax[0][rl], smax[1][rl]);
      }
#pragma unroll
    for (int i = 0; i < 4; i++)
#pragma unroll
      for (int r = 0; r < 4; r++) {
        float s = 0.f;
#pragma unroll
        for (int j = 0; j < 4; j++) {
          float e = __expf(acc[i][j][r] - mx[i][r]);
          acc[i][j][r] = e; s += e;
        }
#pragma unroll
        for (int sh = 1; sh < 16; sh <<= 1) s += __shfl_xor(s, sh);
        if (fr == 0) ssum[wid & 1][wr + i * 16 + fq * 4 + r] = s;
      }
    __syncthreads();
    float inv[4][4];
#pragma unroll
    for (int i = 0; i < 4; i++)
#pragma unroll
      for (int r = 0; r < 4; r++) {
        int rl = wr + i * 16 + fq * 4 + r;
        float S = ssum[0][rl] + ssum[1][rl];
        inv[i][r] = S > 0.f ? 1.f / S : 0.f;
      }
#pragma unroll
    for (int i = 0; i < 4; i++)
#pragma unroll
      for (int j = 0; j < 4; j++) {
        int col = wc + j * 16 + fr;
        int row0 = m0 + wr + i * 16 + fq * 4;
        ushort4v o;
#pragma unroll
        for (int r = 0; r < 4; r++) {
          bool ok = mmr[i][r] && mnc[j];
          float val = ok ? acc[i][j][r] * inv[i][r] : 0.f;
          o[r] = f2bf(val);
          ApB[(long)(row0 + r) * N + col] = o[r];
        }
        *(ushort4v*)(ApTB + (long)col * M + row0) = o;
      }
  } else {  // EPI == 3: plain bf16 C
    unsigned short* CB = Tout + (long)b * M * N;
#pragma unroll
    for (int i = 0; i < 4; i++)
#pragma unroll
      for (int j = 0; j < 4; j++) {
        int col = n0 + wc + j * 16 + fr;
#pragma unroll
        for (int r = 0; r < 4; r++)
          CB[(long)(m0 + wr + i * 16 + fq * 4 + r) * N + col] = f2bf(acc[i][j][r]);
      }
  }
}

// ---------------- col softmax over p (len 512) on UmT rows, wave per row -> BpT bf16 ----------------
__global__ __launch_bounds__(256) void colsoftmaxT_kernel(
    const float* __restrict__ UmT, unsigned short* __restrict__ BpT,
    const int* __restrict__ mp, const int* __restrict__ mq) {
  int wid = blockIdx.x * 4 + (threadIdx.x >> 6);  // = b*LQ + q
  int lane = threadIdx.x & 63;
  int b = wid >> 7;
  const float* row = UmT + (long)wid * LP;
  float v[8];
  float m = NEG_MAX;
#pragma unroll
  for (int i = 0; i < 8; i++) { v[i] = row[lane + 64 * i]; m = fmaxf(m, v[i]); }
#pragma unroll
  for (int off = 32; off; off >>= 1) m = fmaxf(m, __shfl_xor(m, off));
  float e[8];
  float s = 0.f;
#pragma unroll
  for (int i = 0; i < 8; i++) { e[i] = __expf(v[i] - m); s += e[i]; }
#pragma unroll
  for (int off = 32; off; off >>= 1) s += __shfl_xor(s, off);
  float inv = s > 0.f ? 1.f / s : 0.f;
  int mqv = mq[wid];
#pragma unroll
  for (int i = 0; i < 8; i++) {
    int p = lane + 64 * i;
    bool ok = mqv && mp[b * LP + p];
    BpT[(long)wid * LP + p] = ok ? f2bf(e[i] * inv) : 0;
  }
}

// ---------------- fused A-side: A1 = Ap@Eq, A2 = Ap@B1; writes all 5 gqp chunks ----------------
__global__ __launch_bounds__(256) void afused_kernel(
    const unsigned short* __restrict__ Apb, const unsigned short* __restrict__ EqT,
    const unsigned short* __restrict__ B1T, const unsigned short* __restrict__ Epb,
    const int* __restrict__ mp, float* __restrict__ out_gqp) {
  const int b = blockIdx.z;
  const unsigned short* A = Apb + (long)b * LP * LQ;    // [512p][128q]
  const unsigned short* Bq = EqT + (long)b * HDIM * LQ; // [512h][128q]
  const unsigned short* Bb1 = B1T + (long)b * HDIM * LQ;// [512h][128q]
  const int m0 = blockIdx.y * 128, n0 = blockIdx.x * 128;
  __shared__ unsigned short As[8192], Bs1[8192], Bs2[8192];
  const int t = threadIdx.x, lane = t & 63, wid = t >> 6;
  const int wr = (wid >> 1) * 64, wc = (wid & 1) * 64;
  const int fr = lane & 15, fq = lane >> 4;
  f32x4 acc1[4][4] = {}, acc2[4][4] = {};
  for (int k0 = 0; k0 < LQ; k0 += 64) {
    stage128x64(A, LQ, m0, k0, As, t);
    stage128x64(Bq, LQ, n0, k0, Bs1, t);
    stage128x64(Bb1, LQ, n0, k0, Bs2, t);
    __syncthreads();
#pragma unroll
    for (int ks = 0; ks < 2; ks++) {
      short8 af[4], b1f[4], b2f[4];
#pragma unroll
      for (int i = 0; i < 4; i++) {
        af[i] = fragld(As, wr + i * 16 + fr, ks, fq);
        b1f[i] = fragld(Bs1, wc + i * 16 + fr, ks, fq);
        b2f[i] = fragld(Bs2, wc + i * 16 + fr, ks, fq);
      }
#pragma unroll
      for (int i = 0; i < 4; i++)
#pragma unroll
        for (int j = 0; j < 4; j++) {
          acc1[i][j] = __builtin_amdgcn_mfma_f32_16x16x32_bf16(af[i], b1f[j], acc1[i][j], 0, 0, 0);
          acc2[i][j] = __builtin_amdgcn_mfma_f32_16x16x32_bf16(af[i], b2f[j], acc2[i][j], 0, 0, 0);
        }
    }
    __syncthreads();
  }
  float* outB = out_gqp + (long)b * LP * GDIM;
  const unsigned short* EB = Epb + (long)b * LP * HDIM;
  const int* mM = mp + (long)b * LP;
#pragma unroll
  for (int i = 0; i < 4; i++)
#pragma unroll
    for (int r = 0; r < 4; r++) {
      int row = m0 + wr + i * 16 + fq * 4 + r;
      float mm = (float)mM[row];
      float* orow = outB + (long)row * GDIM;
      const unsigned short* erow = EB + (long)row * HDIM;
#pragma unroll
      for (int j = 0; j < 4; j++) {
        int col = n0 + wc + j * 16 + fr;
        float v1 = acc1[i][j][r], v2 = acc2[i][j][r];
        float e = bf2f(erow[col]);
        orow[col] = e * mm;
        orow[HDIM + col] = v1 * mm;
        orow[2 * HDIM + col] = v2 * mm;
        orow[3 * HDIM + col] = e * v1 * mm;
        orow[4 * HDIM + col] = e * v2 * mm;
      }
    }
}

// ---------------- fused B-side: B1 = Bp^T@Ep (K=512), B2 = M2@Eq (K=128); 5 gpq chunks + B1T ----------------
__global__ __launch_bounds__(256) void bfused_kernel(
    const unsigned short* __restrict__ BpT, const unsigned short* __restrict__ EpT,
    const unsigned short* __restrict__ M2g, const unsigned short* __restrict__ EqT,
    const unsigned short* __restrict__ Eqb, const int* __restrict__ mq,
    float* __restrict__ out_gpq, unsigned short* __restrict__ B1T) {
  const int b = blockIdx.z;
  const int n0 = blockIdx.x * 128;
  __shared__ unsigned short As[8192], Bs[8192];
  const int t = threadIdx.x, lane = t & 63, wid = t >> 6;
  const int wr = (wid >> 1) * 64, wc = (wid & 1) * 64;
  const int fr = lane & 15, fq = lane >> 4;
  f32x4 acc1[4][4] = {}, acc2[4][4] = {};
  {  // stream 1: B1 = Bp^T @ Ep over p (K=512)
    const unsigned short* A = BpT + (long)b * LQ * LP;   // [128q][512p]
    const unsigned short* B = EpT + (long)b * HDIM * LP; // [512h][512p]
    for (int k0 = 0; k0 < LP; k0 += 64) {
      stage128x64(A, LP, 0, k0, As, t);
      stage128x64(B, LP, n0, k0, Bs, t);
      __syncthreads();
#pragma unroll
      for (int ks = 0; ks < 2; ks++) {
        short8 af[4], bfv[4];
#pragma unroll
        for (int i = 0; i < 4; i++) {
          af[i] = fragld(As, wr + i * 16 + fr, ks, fq);
          bfv[i] = fragld(Bs, wc + i * 16 + fr, ks, fq);
        }
#pragma unroll
        for (int i = 0; i < 4; i++)
#pragma unroll
          for (int j = 0; j < 4; j++)
            acc1[i][j] = __builtin_amdgcn_mfma_f32_16x16x32_bf16(af[i], bfv[j], acc1[i][j], 0, 0, 0);
      }
      __syncthreads();
    }
  }
  {  // stream 2: B2 = M2 @ Eq over q' (K=128)
    const unsigned short* A = M2g + (long)b * LQ * LQ;   // [128q][128q']
    const unsigned short* B = EqT + (long)b * HDIM * LQ; // [512h][128q']
    for (int k0 = 0; k0 < LQ; k0 += 64) {
      stage128x64(A, LQ, 0, k0, As, t);
      stage128x64(B, LQ, n0, k0, Bs, t);
      __syncthreads();
#pragma unroll
      for (int ks = 0; ks < 2; ks++) {
        short8 af[4], bfv[4];
#pragma unroll
        for (int i = 0; i < 4; i++) {
          af[i] = fragld(As, wr + i * 16 + fr, ks, fq);
          bfv[i] = fragld(Bs, wc + i * 16 + fr, ks, fq);
        }
#pragma unroll
        for (int i = 0; i < 4; i++)
#pragma unroll
          for (int j = 0; j < 4; j++)
            acc2[i][j] = __builtin_amdgcn_mfma_f32_16x16x32_bf16(af[i], bfv[j], acc2[i][j], 0, 0, 0);
      }
      __syncthreads();
    }
  }
  float* outB = out_gpq + (long)b * LQ * GDIM;
  const unsigned short* EB = Eqb + (long)b * LQ * HDIM;
  const int* mM = mq + (long)b * LQ;
  unsigned short* B1TB = B1T + (long)b * HDIM * LQ;
#pragma unroll
  for (int i = 0; i < 4; i++) {
#pragma unroll
    for (int r = 0; r < 4; r++) {
      int row = wr + i * 16 + fq * 4 + r;
      float mm = (float)mM[row];
      float* orow = outB + (long)row * GDIM;
      const unsigned short* erow = EB + (long)row * HDIM;
#pragma unroll
      for (int j = 0; j < 4; j++) {
        int col = n0 + wc + j * 16 + fr;
        float v1 = acc1[i][j][r], v2 = acc2[i][j][r];
        float e = bf2f(erow[col]);
        orow[col] = e * mm;
        orow[HDIM + col] = v1 * mm;
        orow[2 * HDIM + col] = v2 * mm;
        orow[3 * HDIM + col] = e * v1 * mm;
        orow[4 * HDIM + col] = e * v2 * mm;
      }
    }
#pragma unroll
    for (int j = 0; j < 4; j++) {
      int col = n0 + wc + j * 16 + fr;
      int row0 = wr + i * 16 + fq * 4;
      ushort4v o = {f2bf(acc1[i][j][0]), f2bf(acc1[i][j][1]),
                    f2bf(acc1[i][j][2]), f2bf(acc1[i][j][3])};
      *(ushort4v*)(B1TB + (long)col * LQ + row0) = o;
    }
  }
}

extern "C" void kernel_launch(void* const* d_in, const int* in_sizes, int n_in,
                              void* d_out, int out_size, void* d_ws, size_t ws_size,
                              hipStream_t stream) {
  const float* Eq = (const float*)d_in[0];   // (32,128,512)
  const float* Ep = (const float*)d_in[1];   // (32,512,512)
  const int* mq = (const int*)d_in[2];       // (32,128)
  const int* mp = (const int*)d_in[3];       // (32,512)
  const float* w = (const float*)d_in[4];    // (1536,)
  float* out = (float*)d_out;
  float* out_gpq = out;                                  // (32,128,2560)
  float* out_gqp = out + (long)BBATCH * LQ * GDIM;       // (32,512,2560)

  unsigned short* Epb = (unsigned short*)d_ws;  // [32][512p][512h] raw bf16
  unsigned short* EpT = Epb + 32L * 512 * 512;  // [32][512h][512p]
  unsigned short* Eqb = EpT + 32L * 512 * 512;  // [32][128q][512h]
  unsigned short* EqT = Eqb + 32L * 128 * 512;  // [32][512h][128q]
  unsigned short* Eqw = EqT + 32L * 128 * 512;  // [32][128q][512h] * wm
  unsigned short* Apb = Eqw + 32L * 128 * 512;  // [32][512p][128q]
  unsigned short* ApT = Apb + 32L * 512 * 128;  // [32][128q][512p]
  unsigned short* BpT = ApT + 32L * 512 * 128;  // [32][128q][512p]
  unsigned short* B1T = BpT + 32L * 128 * 512;  // [32][512h][128q]
  unsigned short* M2  = B1T + 32L * 512 * 128;  // [32][128q][128q']
  float* UmT = (float*)(M2 + 32L * 128 * 128);  // [32][128q][512p]
  float* epb = UmT + 32L * 128 * 512;           // [32][512]
  float* eqb2 = epb + 32L * 512;                // [32][128]

  // 0. zero bias accumulators (atomics target)
  hipMemsetAsync(epb, 0, (32L * 512 + 32L * 128) * sizeof(float), stream);

  // 1. casts + fused bias dots
  cast_kernel<512, false><<<dim3(8, 8, BBATCH), 256, 0, stream>>>(
      Ep, w + HDIM, nullptr, Epb, EpT, nullptr, epb);
  cast_kernel<128, true><<<dim3(8, 2, BBATCH), 256, 0, stream>>>(
      Eq, w, w + 2 * HDIM, Eqb, EqT, Eqw, eqb2);

  // 2. U GEMM + fused row-softmax: -> Apb, ApT, UmT
  mfma_gemm<0><<<dim3(1, 4, BBATCH), 256, 0, stream>>>(
      Epb, Eqw, LP, LQ, HDIM, epb, eqb2, mp, mq, UmT, Apb, ApT, nullptr);

  // 3. col softmax -> BpT
  colsoftmaxT_kernel<<<BBATCH * LQ / 4, 256, 0, stream>>>(UmT, BpT, mp, mq);

  // 4. M2 = Bp^T @ Ap  (128x128, K=512) -> bf16
  mfma_gemm<3><<<dim3(1, 1, BBATCH), 256, 0, stream>>>(
      BpT, ApT, LQ, LQ, LP, nullptr, nullptr, nullptr, nullptr,
      nullptr, nullptr, nullptr, M2);

  // 5. fused B-side: B1 + B2 -> all 5 gpq chunks + B1T
  bfused_kernel<<<dim3(4, 1, BBATCH), 256, 0, stream>>>(
      BpT, EpT, M2, EqT, Eqb, mq, out_gpq, B1T);

  // 6. fused A-side: A1 + A2 -> all 5 gqp chunks
  afused_kernel<<<dim3(4, 4, BBATCH), 256, 0, stream>>>(
      Apb, EqT, B1T, Epb, mp, out_gqp);
}

// Round 5
// 138.758 us; speedup vs baseline: 1.0843x; 1.0065x over previous
//
#include <hip/hip_runtime.h>
#include <hip/hip_bf16.h>

// Problem constants: B=8, NUM=4 -> BB=32 batches; LQ=128, LP=512, H=512.
#define BBATCH 32
#define LQ 128
#define LP 512
#define HDIM 512
#define GDIM 2560   // 5*H concat width
#define NEG_MAX (-3.402823466e38f)

typedef __attribute__((ext_vector_type(8))) short short8;
typedef __attribute__((ext_vector_type(4))) float f32x4;
typedef __attribute__((ext_vector_type(4))) unsigned short ushort4v;

__device__ inline unsigned short f2bf(float f) {
  union { float f; unsigned int u; } v; v.f = f;
  unsigned int r = v.u + 0x7FFFu + ((v.u >> 16) & 1u);  // RNE
  return (unsigned short)(r >> 16);
}
__device__ inline float bf2f(unsigned short s) {
  union { unsigned int u; float f; } v; v.u = (unsigned int)s << 16;
  return v.f;
}

// ---- shared staging / fragment helpers (128 rows x 64 k bf16 tile, XOR-swizzled) ----
__device__ inline void stage128x64(const unsigned short* __restrict__ src, int ld,
                                   int row0, int k0, unsigned short* lds, int t) {
#pragma unroll
  for (int i = 0; i < 4; i++) {
    int o = (t + i * 256) * 16;
    int row = o >> 7, col = (o & 127) >> 1;
    int swz = o ^ ((row & 7) << 4);
    *(short8*)((char*)lds + swz) = *(const short8*)(src + (long)(row0 + row) * ld + k0 + col);
  }
}
__device__ inline short8 fragld(const unsigned short* lds, int row, int ks, int fq) {
  return *(const short8*)((const char*)lds + (((row << 7) + ks * 64 + fq * 16) ^ ((row & 7) << 4)));
}

// ---------------- merged cast: Ep & Eq f32 -> bf16 {normal, transposed, (Eq: *wm)} + exact f32 bias dots ----------------
// grid (10, BBATCH): bx<8 -> Ep row-tile p0=bx*64; bx>=8 -> Eq row-tile p0=(bx-8)*64.
// Each block owns complete rows (loops all 8 h-tiles) -> bias dot needs no atomics.
__global__ __launch_bounds__(256) void cast2_kernel(
    const float* __restrict__ Ep, const float* __restrict__ Eq,
    const float* __restrict__ w,
    unsigned short* __restrict__ Epb, unsigned short* __restrict__ EpT,
    unsigned short* __restrict__ Eqb, unsigned short* __restrict__ EqT,
    unsigned short* __restrict__ Eqw,
    float* __restrict__ epv, float* __restrict__ eqv) {
  const int b = blockIdx.y;
  const int bx = blockIdx.x;
  const bool isP = bx < 8;
  const int R = isP ? LP : LQ;
  const int p0 = (isP ? bx : bx - 8) * 64;
  const float* src = isP ? Ep + (long)b * LP * HDIM : Eq + (long)b * LQ * HDIM;
  const float* wb_base = isP ? w + HDIM : w;  // w_p for Ep rows, w_q for Eq rows
  unsigned short* dN = isP ? Epb + (long)b * LP * HDIM : Eqb + (long)b * LQ * HDIM;
  unsigned short* dT = isP ? EpT + (long)b * HDIM * LP : EqT + (long)b * HDIM * LQ;
  unsigned short* dW = isP ? nullptr : Eqw + (long)b * LQ * HDIM;
  float* bias = (isP ? epv + b * LP : eqv + b * LQ) + p0;
  __shared__ float T[64][65];
  const int t = threadIdx.x, c4 = (t & 15) * 4, r = t >> 4;
  float dot[4] = {0.f, 0.f, 0.f, 0.f};
  for (int h0 = 0; h0 < HDIM; h0 += 64) {
    float4 wb = *(const float4*)(wb_base + h0 + c4);
    float4 wm4 = {0, 0, 0, 0};
    if (!isP) wm4 = *(const float4*)(w + 2 * HDIM + h0 + c4);
    __syncthreads();  // previous iteration's T reads complete
#pragma unroll
    for (int i = 0; i < 4; i++) {
      int row = r + 16 * i;
      float4 v = *(const float4*)(src + (long)(p0 + row) * HDIM + h0 + c4);
      T[row][c4] = v.x; T[row][c4 + 1] = v.y; T[row][c4 + 2] = v.z; T[row][c4 + 3] = v.w;
      ushort4v o = {f2bf(v.x), f2bf(v.y), f2bf(v.z), f2bf(v.w)};
      *(ushort4v*)(dN + (long)(p0 + row) * HDIM + h0 + c4) = o;
      if (!isP) {
        ushort4v ow = {f2bf(v.x * wm4.x), f2bf(v.y * wm4.y), f2bf(v.z * wm4.z), f2bf(v.w * wm4.w)};
        *(ushort4v*)(dW + (long)(p0 + row) * HDIM + h0 + c4) = ow;
      }
      dot[i] += v.x * wb.x + v.y * wb.y + v.z * wb.z + v.w * wb.w;
    }
    __syncthreads();
#pragma unroll
    for (int i = 0; i < 4; i++) {
      int hh = r + 16 * i;
      ushort4v o = {f2bf(T[c4][hh]), f2bf(T[c4 + 1][hh]), f2bf(T[c4 + 2][hh]), f2bf(T[c4 + 3][hh])};
      *(ushort4v*)(dT + (long)(h0 + hh) * R + p0 + c4) = o;
    }
  }
#pragma unroll
  for (int i = 0; i < 4; i++) {
#pragma unroll
    for (int s = 1; s < 16; s <<= 1) dot[i] += __shfl_xor(dot[i], s);
  }
  if ((t & 15) == 0) {
#pragma unroll
    for (int i = 0; i < 4; i++) bias[r + 16 * i] = dot[i];
  }
}

// ---------------- MFMA NT GEMM: U + fused row-softmax ----------------
// A [M][K], B [N][K] bf16; N==128, grid.x==1. Outputs Apb [p][q], ApT [q][p] bf16; UmT [q][p] f32.
__global__ __launch_bounds__(256) void u_gemm(
    const unsigned short* __restrict__ Ab, const unsigned short* __restrict__ Bb,
    int M, int N, int K,
    const float* __restrict__ epv, const float* __restrict__ eqv,
    const int* __restrict__ maskM, const int* __restrict__ maskN,
    float* __restrict__ UmT, unsigned short* __restrict__ Apb,
    unsigned short* __restrict__ ApT) {
  const int b = blockIdx.z;
  const unsigned short* A = Ab + (long)b * M * K;
  const unsigned short* B = Bb + (long)b * N * K;
  const int m0 = blockIdx.y * 128;
  __shared__ unsigned short As[8192];
  __shared__ unsigned short Bs[8192];
  const int t = threadIdx.x, lane = t & 63, wid = t >> 6;
  const int wr = (wid >> 1) * 64, wc = (wid & 1) * 64;
  const int fr = lane & 15, fq = lane >> 4;
  f32x4 acc[4][4] = {};
  for (int k0 = 0; k0 < K; k0 += 64) {
    stage128x64(A, K, m0, k0, As, t);
    stage128x64(B, K, 0, k0, Bs, t);
    __syncthreads();
#pragma unroll
    for (int ks = 0; ks < 2; ks++) {
      short8 af[4], bfv[4];
#pragma unroll
      for (int i = 0; i < 4; i++) {
        af[i] = fragld(As, wr + i * 16 + fr, ks, fq);
        bfv[i] = fragld(Bs, wc + i * 16 + fr, ks, fq);
      }
#pragma unroll
      for (int i = 0; i < 4; i++)
#pragma unroll
        for (int j = 0; j < 4; j++)
          acc[i][j] = __builtin_amdgcn_mfma_f32_16x16x32_bf16(af[i], bfv[j], acc[i][j], 0, 0, 0);
    }
    __syncthreads();
  }
  __shared__ float smax[2][128], ssum[2][128];
  const float* ep_b = epv + (long)b * M;
  const float* eq_b = eqv + (long)b * N;
  const int* mM = maskM + (long)b * M;
  const int* mN = maskN + (long)b * N;
  float* UmTB = UmT + (long)b * M * N;
  unsigned short* ApB = Apb + (long)b * M * N;
  unsigned short* ApTB = ApT + (long)b * M * N;
  float eqc[4]; int mnc[4];
#pragma unroll
  for (int j = 0; j < 4; j++) {
    int col = wc + j * 16 + fr;
    eqc[j] = eq_b[col]; mnc[j] = mN[col];
  }
  float epr[4][4]; int mmr[4][4];
#pragma unroll
  for (int i = 0; i < 4; i++)
#pragma unroll
    for (int r = 0; r < 4; r++) {
      int row = m0 + wr + i * 16 + fq * 4 + r;
      epr[i][r] = ep_b[row]; mmr[i][r] = mM[row];
    }
#pragma unroll
  for (int i = 0; i < 4; i++)
#pragma unroll
    for (int j = 0; j < 4; j++) {
      float4 tv;
#pragma unroll
      for (int r = 0; r < 4; r++) {
        float a = acc[i][j][r];
        bool ok = mmr[i][r] && mnc[j];
        ((float*)&tv)[r] = ok ? a + epr[i][r] : NEG_MAX;
        acc[i][j][r] = ok ? a + eqc[j] : NEG_MAX;
      }
      int col = wc + j * 16 + fr;
      *(float4*)(UmTB + (long)col * M + m0 + wr + i * 16 + fq * 4) = tv;
    }
  float mx[4][4];
#pragma unroll
  for (int i = 0; i < 4; i++)
#pragma unroll
    for (int r = 0; r < 4; r++) {
      float m = fmaxf(fmaxf(acc[i][0][r], acc[i][1][r]), fmaxf(acc[i][2][r], acc[i][3][r]));
#pragma unroll
      for (int s = 1; s < 16; s <<= 1) m = fmaxf(m, __shfl_xor(m, s));
      mx[i][r] = m;
      if (fr == 0) smax[wid & 1][wr + i * 16 + fq * 4 + r] = m;
    }
  __syncthreads();
#pragma unroll
  for (int i = 0; i < 4; i++)
#pragma unroll
    for (int r = 0; r < 4; r++) {
      int rl = wr + i * 16 + fq * 4 + r;
      mx[i][r] = fmaxf(smax[0][rl], smax[1][rl]);
    }
#pragma unroll
  for (int i = 0; i < 4; i++)
#pragma unroll
    for (int r = 0; r < 4; r++) {
      float s = 0.f;
#pragma unroll
      for (int j = 0; j < 4; j++) {
        float e = __expf(acc[i][j][r] - mx[i][r]);
        acc[i][j][r] = e; s += e;
      }
#pragma unroll
      for (int sh = 1; sh < 16; sh <<= 1) s += __shfl_xor(s, sh);
      if (fr == 0) ssum[wid & 1][wr + i * 16 + fq * 4 + r] = s;
    }
  __syncthreads();
  float inv[4][4];
#pragma unroll
  for (int i = 0; i < 4; i++)
#pragma unroll
    for (int r = 0; r < 4; r++) {
      int rl = wr + i * 16 + fq * 4 + r;
      float S = ssum[0][rl] + ssum[1][rl];
      inv[i][r] = S > 0.f ? 1.f / S : 0.f;
    }
#pragma unroll
  for (int i = 0; i < 4; i++)
#pragma unroll
    for (int j = 0; j < 4; j++) {
      int col = wc + j * 16 + fr;
      int row0 = m0 + wr + i * 16 + fq * 4;
      ushort4v o;
#pragma unroll
      for (int r = 0; r < 4; r++) {
        bool ok = mmr[i][r] && mnc[j];
        float val = ok ? acc[i][j][r] * inv[i][r] : 0.f;
        o[r] = f2bf(val);
        ApB[(long)(row0 + r) * N + col] = o[r];
      }
      *(ushort4v*)(ApTB + (long)col * M + row0) = o;
    }
}

// ---------------- col softmax over p (len 512) on UmT rows, wave per row -> BpT bf16 ----------------
__global__ __launch_bounds__(256) void colsoftmaxT_kernel(
    const float* __restrict__ UmT, unsigned short* __restrict__ BpT,
    const int* __restrict__ mp, const int* __restrict__ mq) {
  int wid = blockIdx.x * 4 + (threadIdx.x >> 6);  // = b*LQ + q
  int lane = threadIdx.x & 63;
  int b = wid >> 7;
  const float* row = UmT + (long)wid * LP;
  float v[8];
  float m = NEG_MAX;
#pragma unroll
  for (int i = 0; i < 8; i++) { v[i] = row[lane + 64 * i]; m = fmaxf(m, v[i]); }
#pragma unroll
  for (int off = 32; off; off >>= 1) m = fmaxf(m, __shfl_xor(m, off));
  float e[8];
  float s = 0.f;
#pragma unroll
  for (int i = 0; i < 8; i++) { e[i] = __expf(v[i] - m); s += e[i]; }
#pragma unroll
  for (int off = 32; off; off >>= 1) s += __shfl_xor(s, off);
  float inv = s > 0.f ? 1.f / s : 0.f;
  int mqv = mq[wid];
#pragma unroll
  for (int i = 0; i < 8; i++) {
    int p = lane + 64 * i;
    bool ok = mqv && mp[b * LP + p];
    BpT[(long)wid * LP + p] = ok ? f2bf(e[i] * inv) : 0;
  }
}

// ---------------- fused B-side v3: B1 = Bp^T@Ep and M2 = Bp^T@Ap (K=512, co-staged),
//                  then B2 = M2@Eq (K=128, M2 from LDS); writes all 5 gpq chunks + B1T ----------------
__global__ __launch_bounds__(256) void bfused_kernel(
    const unsigned short* __restrict__ BpT, const unsigned short* __restrict__ EpT,
    const unsigned short* __restrict__ ApT, const unsigned short* __restrict__ EqT,
    const unsigned short* __restrict__ Eqb, const int* __restrict__ mq,
    float* __restrict__ out_gpq, unsigned short* __restrict__ B1T) {
  const int b = blockIdx.z;
  const int n0 = blockIdx.x * 128;
  __shared__ unsigned short As[8192], Bs[8192], Bs2[8192];
  __shared__ unsigned short M2l[16384];  // [128 q][128 q'] bf16, 256B rows, XOR-swizzled
  const int t = threadIdx.x, lane = t & 63, wid = t >> 6;
  const int wr = (wid >> 1) * 64, wc = (wid & 1) * 64;
  const int fr = lane & 15, fq = lane >> 4;
  f32x4 acc1[4][4] = {}, accm[4][4] = {};
  {  // phase 1: K=512 over p; acc1 = B1 tile (vs EpT), accm = M2 (vs ApT)
    const unsigned short* A = BpT + (long)b * LQ * LP;   // [128q][512p]
    const unsigned short* B = EpT + (long)b * HDIM * LP; // [512h][512p]
    const unsigned short* B2 = ApT + (long)b * LQ * LP;  // [128q'][512p]
    for (int k0 = 0; k0 < LP; k0 += 64) {
      stage128x64(A, LP, 0, k0, As, t);
      stage128x64(B, LP, n0, k0, Bs, t);
      stage128x64(B2, LP, 0, k0, Bs2, t);
      __syncthreads();
#pragma unroll
      for (int ks = 0; ks < 2; ks++) {
        short8 af[4], bfv[4], mfv[4];
#pragma unroll
        for (int i = 0; i < 4; i++) {
          af[i] = fragld(As, wr + i * 16 + fr, ks, fq);
          bfv[i] = fragld(Bs, wc + i * 16 + fr, ks, fq);
          mfv[i] = fragld(Bs2, wc + i * 16 + fr, ks, fq);
        }
#pragma unroll
        for (int i = 0; i < 4; i++)
#pragma unroll
          for (int j = 0; j < 4; j++) {
            acc1[i][j] = __builtin_amdgcn_mfma_f32_16x16x32_bf16(af[i], bfv[j], acc1[i][j], 0, 0, 0);
            accm[i][j] = __builtin_amdgcn_mfma_f32_16x16x32_bf16(af[i], mfv[j], accm[i][j], 0, 0, 0);
          }
      }
      __syncthreads();
    }
  }
  // dump M2 (bf16) into swizzled LDS [128][128]
#pragma unroll
  for (int i = 0; i < 4; i++)
#pragma unroll
    for (int j = 0; j < 4; j++) {
      int col = wc + j * 16 + fr;
#pragma unroll
      for (int r = 0; r < 4; r++) {
        int row = wr + i * 16 + fq * 4 + r;
        int byte = (row << 8) + col * 2;
        byte ^= (row & 7) << 4;
        *(unsigned short*)((char*)M2l + byte) = f2bf(accm[i][j][r]);
      }
    }
  __syncthreads();
  // phase 2: B2 = M2 @ EqT[n0 tile], K=128 (M2 A-frags from LDS)
  f32x4 acc2[4][4] = {};
  {
    const unsigned short* BE = EqT + (long)b * HDIM * LQ;  // [512h][128q']
    for (int k0 = 0; k0 < LQ; k0 += 64) {
      stage128x64(BE, LQ, n0, k0, Bs, t);
      __syncthreads();
#pragma unroll
      for (int ks = 0; ks < 2; ks++) {
        short8 af[4], bfv[4];
#pragma unroll
        for (int i = 0; i < 4; i++) {
          int row = wr + i * 16 + fr;
          int byte = ((row << 8) + k0 * 2 + ks * 64 + fq * 16) ^ ((row & 7) << 4);
          af[i] = *(const short8*)((const char*)M2l + byte);
          bfv[i] = fragld(Bs, wc + i * 16 + fr, ks, fq);
        }
#pragma unroll
        for (int i = 0; i < 4; i++)
#pragma unroll
          for (int j = 0; j < 4; j++)
            acc2[i][j] = __builtin_amdgcn_mfma_f32_16x16x32_bf16(af[i], bfv[j], acc2[i][j], 0, 0, 0);
      }
      __syncthreads();
    }
  }
  // epilogue: all 5 gpq chunks + B1T
  float* outB = out_gpq + (long)b * LQ * GDIM;
  const unsigned short* EB = Eqb + (long)b * LQ * HDIM;
  const int* mM = mq + (long)b * LQ;
  unsigned short* B1TB = B1T + (long)b * HDIM * LQ;
#pragma unroll
  for (int i = 0; i < 4; i++) {
#pragma unroll
    for (int r = 0; r < 4; r++) {
      int row = wr + i * 16 + fq * 4 + r;
      float mm = (float)mM[row];
      float* orow = outB + (long)row * GDIM;
      const unsigned short* erow = EB + (long)row * HDIM;
#pragma unroll
      for (int j = 0; j < 4; j++) {
        int col = n0 + wc + j * 16 + fr;
        float v1 = acc1[i][j][r], v2 = acc2[i][j][r];
        float e = bf2f(erow[col]);
        orow[col] = e * mm;
        orow[HDIM + col] = v1 * mm;
        orow[2 * HDIM + col] = v2 * mm;
        orow[3 * HDIM + col] = e * v1 * mm;
        orow[4 * HDIM + col] = e * v2 * mm;
      }
    }
#pragma unroll
    for (int j = 0; j < 4; j++) {
      int col = n0 + wc + j * 16 + fr;
      int row0 = wr + i * 16 + fq * 4;
      ushort4v o = {f2bf(acc1[i][j][0]), f2bf(acc1[i][j][1]),
                    f2bf(acc1[i][j][2]), f2bf(acc1[i][j][3])};
      *(ushort4v*)(B1TB + (long)col * LQ + row0) = o;
    }
  }
}

// ---------------- fused A-side: A1 = Ap@Eq, A2 = Ap@B1; writes all 5 gqp chunks ----------------
__global__ __launch_bounds__(256) void afused_kernel(
    const unsigned short* __restrict__ Apb, const unsigned short* __restrict__ EqT,
    const unsigned short* __restrict__ B1T, const unsigned short* __restrict__ Epb,
    const int* __restrict__ mp, float* __restrict__ out_gqp) {
  const int b = blockIdx.z;
  const unsigned short* A = Apb + (long)b * LP * LQ;    // [512p][128q]
  const unsigned short* Bq = EqT + (long)b * HDIM * LQ; // [512h][128q]
  const unsigned short* Bb1 = B1T + (long)b * HDIM * LQ;// [512h][128q]
  const int m0 = blockIdx.y * 128, n0 = blockIdx.x * 128;
  __shared__ unsigned short As[8192], Bs1[8192], Bs2[8192];
  const int t = threadIdx.x, lane = t & 63, wid = t >> 6;
  const int wr = (wid >> 1) * 64, wc = (wid & 1) * 64;
  const int fr = lane & 15, fq = lane >> 4;
  f32x4 acc1[4][4] = {}, acc2[4][4] = {};
  for (int k0 = 0; k0 < LQ; k0 += 64) {
    stage128x64(A, LQ, m0, k0, As, t);
    stage128x64(Bq, LQ, n0, k0, Bs1, t);
    stage128x64(Bb1, LQ, n0, k0, Bs2, t);
    __syncthreads();
#pragma unroll
    for (int ks = 0; ks < 2; ks++) {
      short8 af[4], b1f[4], b2f[4];
#pragma unroll
      for (int i = 0; i < 4; i++) {
        af[i] = fragld(As, wr + i * 16 + fr, ks, fq);
        b1f[i] = fragld(Bs1, wc + i * 16 + fr, ks, fq);
        b2f[i] = fragld(Bs2, wc + i * 16 + fr, ks, fq);
      }
#pragma unroll
      for (int i = 0; i < 4; i++)
#pragma unroll
        for (int j = 0; j < 4; j++) {
          acc1[i][j] = __builtin_amdgcn_mfma_f32_16x16x32_bf16(af[i], b1f[j], acc1[i][j], 0, 0, 0);
          acc2[i][j] = __builtin_amdgcn_mfma_f32_16x16x32_bf16(af[i], b2f[j], acc2[i][j], 0, 0, 0);
        }
    }
    __syncthreads();
  }
  float* outB = out_gqp + (long)b * LP * GDIM;
  const unsigned short* EB = Epb + (long)b * LP * HDIM;
  const int* mM = mp + (long)b * LP;
#pragma unroll
  for (int i = 0; i < 4; i++)
#pragma unroll
    for (int r = 0; r < 4; r++) {
      int row = m0 + wr + i * 16 + fq * 4 + r;
      float mm = (float)mM[row];
      float* orow = outB + (long)row * GDIM;
      const unsigned short* erow = EB + (long)row * HDIM;
#pragma unroll
      for (int j = 0; j < 4; j++) {
        int col = n0 + wc + j * 16 + fr;
        float v1 = acc1[i][j][r], v2 = acc2[i][j][r];
        float e = bf2f(erow[col]);
        orow[col] = e * mm;
        orow[HDIM + col] = v1 * mm;
        orow[2 * HDIM + col] = v2 * mm;
        orow[3 * HDIM + col] = e * v1 * mm;
        orow[4 * HDIM + col] = e * v2 * mm;
      }
    }
}

extern "C" void kernel_launch(void* const* d_in, const int* in_sizes, int n_in,
                              void* d_out, int out_size, void* d_ws, size_t ws_size,
                              hipStream_t stream) {
  const float* Eq = (const float*)d_in[0];   // (32,128,512)
  const float* Ep = (const float*)d_in[1];   // (32,512,512)
  const int* mq = (const int*)d_in[2];       // (32,128)
  const int* mp = (const int*)d_in[3];       // (32,512)
  const float* w = (const float*)d_in[4];    // (1536,)
  float* out = (float*)d_out;
  float* out_gpq = out;                                  // (32,128,2560)
  float* out_gqp = out + (long)BBATCH * LQ * GDIM;       // (32,512,2560)

  unsigned short* Epb = (unsigned short*)d_ws;  // [32][512p][512h] raw bf16
  unsigned short* EpT = Epb + 32L * 512 * 512;  // [32][512h][512p]
  unsigned short* Eqb = EpT + 32L * 512 * 512;  // [32][128q][512h]
  unsigned short* EqT = Eqb + 32L * 128 * 512;  // [32][512h][128q]
  unsigned short* Eqw = EqT + 32L * 512 * 128;  // [32][128q][512h] * wm
  unsigned short* Apb = Eqw + 32L * 128 * 512;  // [32][512p][128q]
  unsigned short* ApT = Apb + 32L * 512 * 128;  // [32][128q][512p]
  unsigned short* BpT = ApT + 32L * 512 * 128;  // [32][128q][512p]
  unsigned short* B1T = BpT + 32L * 128 * 512;  // [32][512h][128q]
  float* UmT = (float*)(B1T + 32L * 512 * 128); // [32][128q][512p]
  float* epb = UmT + 32L * 128 * 512;           // [32][512]
  float* eqb2 = epb + 32L * 512;                // [32][128]

  // 1. merged casts + exact f32 bias dots (no atomics, no memset)
  cast2_kernel<<<dim3(10, BBATCH), 256, 0, stream>>>(
      Ep, Eq, w, Epb, EpT, Eqb, EqT, Eqw, epb, eqb2);

  // 2. U GEMM + fused row-softmax: -> Apb, ApT, UmT
  u_gemm<<<dim3(1, 4, BBATCH), 256, 0, stream>>>(
      Epb, Eqw, LP, LQ, HDIM, epb, eqb2, mp, mq, UmT, Apb, ApT);

  // 3. col softmax -> BpT
  colsoftmaxT_kernel<<<BBATCH * LQ / 4, 256, 0, stream>>>(UmT, BpT, mp, mq);

  // 4. fused B-side: B1 + M2 (co-staged) + B2 -> all 5 gpq chunks + B1T
  bfused_kernel<<<dim3(4, 1, BBATCH), 256, 0, stream>>>(
      BpT, EpT, ApT, EqT, Eqb, mq, out_gpq, B1T);

  // 5. fused A-side: A1 + A2 -> all 5 gqp chunks
  afused_kernel<<<dim3(4, 4, BBATCH), 256, 0, stream>>>(
      Apb, EqT, B1T, Epb, mp, out_gqp);
}

// Round 6
// 137.340 us; speedup vs baseline: 1.0955x; 1.0103x over previous
//
#include <hip/hip_runtime.h>
#include <hip/hip_bf16.h>

// Problem constants: B=8, NUM=4 -> BB=32 batches; LQ=128, LP=512, H=512.
#define BBATCH 32
#define LQ 128
#define LP 512
#define HDIM 512
#define GDIM 2560   // 5*H concat width
#define NEG_MAX (-3.402823466e38f)

typedef __attribute__((ext_vector_type(8))) short short8;
typedef __attribute__((ext_vector_type(4))) float f32x4;
typedef __attribute__((ext_vector_type(4))) unsigned short ushort4v;

__device__ inline unsigned short f2bf(float f) {
  union { float f; unsigned int u; } v; v.f = f;
  unsigned int r = v.u + 0x7FFFu + ((v.u >> 16) & 1u);  // RNE
  return (unsigned short)(r >> 16);
}
__device__ inline float bf2f(unsigned short s) {
  union { unsigned int u; float f; } v; v.u = (unsigned int)s << 16;
  return v.f;
}

// ---- staging / fragment helpers (rows x 64 k bf16 tiles, XOR-swizzled, 128B rows) ----
__device__ inline void stage128x64(const unsigned short* __restrict__ src, int ld,
                                   int row0, int k0, unsigned short* lds, int t) {
#pragma unroll
  for (int i = 0; i < 4; i++) {
    int o = (t + i * 256) * 16;
    int row = o >> 7, col = (o & 127) >> 1;
    int swz = o ^ ((row & 7) << 4);
    *(short8*)((char*)lds + swz) = *(const short8*)(src + (long)(row0 + row) * ld + k0 + col);
  }
}
__device__ inline void stage64x64(const unsigned short* __restrict__ src, int ld,
                                  int row0, int k0, unsigned short* lds, int t) {
#pragma unroll
  for (int i = 0; i < 2; i++) {
    int o = (t + i * 256) * 16;
    int row = o >> 7, col = (o & 127) >> 1;
    int swz = o ^ ((row & 7) << 4);
    *(short8*)((char*)lds + swz) = *(const short8*)(src + (long)(row0 + row) * ld + k0 + col);
  }
}
__device__ inline short8 fragld(const unsigned short* lds, int row, int ks, int fq) {
  return *(const short8*)((const char*)lds + (((row << 7) + ks * 64 + fq * 16) ^ ((row & 7) << 4)));
}

// ---------------- merged cast: Ep & Eq f32 -> bf16 {normal, transposed, (Eq: *wm)} + exact f32 bias dots ----------------
__global__ __launch_bounds__(256) void cast2_kernel(
    const float* __restrict__ Ep, const float* __restrict__ Eq,
    const float* __restrict__ w,
    unsigned short* __restrict__ Epb, unsigned short* __restrict__ EpT,
    unsigned short* __restrict__ Eqb, unsigned short* __restrict__ EqT,
    unsigned short* __restrict__ Eqw,
    float* __restrict__ epv, float* __restrict__ eqv) {
  const int b = blockIdx.y;
  const int bx = blockIdx.x;
  const bool isP = bx < 8;
  const int R = isP ? LP : LQ;
  const int p0 = (isP ? bx : bx - 8) * 64;
  const float* src = isP ? Ep + (long)b * LP * HDIM : Eq + (long)b * LQ * HDIM;
  const float* wb_base = isP ? w + HDIM : w;
  unsigned short* dN = isP ? Epb + (long)b * LP * HDIM : Eqb + (long)b * LQ * HDIM;
  unsigned short* dT = isP ? EpT + (long)b * HDIM * LP : EqT + (long)b * HDIM * LQ;
  unsigned short* dW = isP ? nullptr : Eqw + (long)b * LQ * HDIM;
  float* bias = (isP ? epv + b * LP : eqv + b * LQ) + p0;
  __shared__ float T[64][65];
  const int t = threadIdx.x, c4 = (t & 15) * 4, r = t >> 4;
  float dot[4] = {0.f, 0.f, 0.f, 0.f};
  for (int h0 = 0; h0 < HDIM; h0 += 64) {
    float4 wb = *(const float4*)(wb_base + h0 + c4);
    float4 wm4 = {0, 0, 0, 0};
    if (!isP) wm4 = *(const float4*)(w + 2 * HDIM + h0 + c4);
    __syncthreads();
#pragma unroll
    for (int i = 0; i < 4; i++) {
      int row = r + 16 * i;
      float4 v = *(const float4*)(src + (long)(p0 + row) * HDIM + h0 + c4);
      T[row][c4] = v.x; T[row][c4 + 1] = v.y; T[row][c4 + 2] = v.z; T[row][c4 + 3] = v.w;
      ushort4v o = {f2bf(v.x), f2bf(v.y), f2bf(v.z), f2bf(v.w)};
      *(ushort4v*)(dN + (long)(p0 + row) * HDIM + h0 + c4) = o;
      if (!isP) {
        ushort4v ow = {f2bf(v.x * wm4.x), f2bf(v.y * wm4.y), f2bf(v.z * wm4.z), f2bf(v.w * wm4.w)};
        *(ushort4v*)(dW + (long)(p0 + row) * HDIM + h0 + c4) = ow;
      }
      dot[i] += v.x * wb.x + v.y * wb.y + v.z * wb.z + v.w * wb.w;
    }
    __syncthreads();
#pragma unroll
    for (int i = 0; i < 4; i++) {
      int hh = r + 16 * i;
      ushort4v o = {f2bf(T[c4][hh]), f2bf(T[c4 + 1][hh]), f2bf(T[c4 + 2][hh]), f2bf(T[c4 + 3][hh])};
      *(ushort4v*)(dT + (long)(h0 + hh) * R + p0 + c4) = o;
    }
  }
#pragma unroll
  for (int i = 0; i < 4; i++) {
#pragma unroll
    for (int s = 1; s < 16; s <<= 1) dot[i] += __shfl_xor(dot[i], s);
  }
  if ((t & 15) == 0) {
#pragma unroll
    for (int i = 0; i < 4; i++) bias[r + 16 * i] = dot[i];
  }
}

// ---------------- U GEMM (64-row M-tile) + fused row-softmax ----------------
// A = Epb [512p][512h], B = Eqw [128q][512h]. Tile 64(p) x 128(q), K=512.
// Outputs: Apb [p][q] bf16; UmT [q][p] f32 = masked(acc+ep).
__global__ __launch_bounds__(256) void u_gemm(
    const unsigned short* __restrict__ Ab, const unsigned short* __restrict__ Bb,
    const float* __restrict__ epv, const float* __restrict__ eqv,
    const int* __restrict__ maskM, const int* __restrict__ maskN,
    float* __restrict__ UmT, unsigned short* __restrict__ Apb) {
  const int b = blockIdx.z;
  const unsigned short* A = Ab + (long)b * LP * HDIM;
  const unsigned short* B = Bb + (long)b * LQ * HDIM;
  const int m0 = blockIdx.y * 64;
  __shared__ unsigned short As[4096];  // 64 x 64
  __shared__ unsigned short Bs[8192];  // 128 x 64
  __shared__ float smax[2][64], ssum[2][64];
  const int t = threadIdx.x, lane = t & 63, wid = t >> 6;
  const int wm = wid >> 1, wn = wid & 1;
  const int wr = wm * 32, wc = wn * 64;
  const int fr = lane & 15, fq = lane >> 4;
  f32x4 acc[2][4] = {};
  for (int k0 = 0; k0 < HDIM; k0 += 64) {
    stage64x64(A, HDIM, m0, k0, As, t);
    stage128x64(B, HDIM, 0, k0, Bs, t);
    __syncthreads();
#pragma unroll
    for (int ks = 0; ks < 2; ks++) {
      short8 af[2], bfv[4];
#pragma unroll
      for (int i = 0; i < 2; i++) af[i] = fragld(As, wr + i * 16 + fr, ks, fq);
#pragma unroll
      for (int j = 0; j < 4; j++) bfv[j] = fragld(Bs, wc + j * 16 + fr, ks, fq);
#pragma unroll
      for (int i = 0; i < 2; i++)
#pragma unroll
        for (int j = 0; j < 4; j++)
          acc[i][j] = __builtin_amdgcn_mfma_f32_16x16x32_bf16(af[i], bfv[j], acc[i][j], 0, 0, 0);
    }
    __syncthreads();
  }
  const float* ep_b = epv + (long)b * LP;
  const float* eq_b = eqv + (long)b * LQ;
  const int* mM = maskM + (long)b * LP;
  const int* mN = maskN + (long)b * LQ;
  float* UmTB = UmT + (long)b * LQ * LP;        // [q][p]
  unsigned short* ApB = Apb + (long)b * LP * LQ; // [p][q]
  float eqc[4]; int mnc[4];
#pragma unroll
  for (int j = 0; j < 4; j++) {
    int col = wc + j * 16 + fr;
    eqc[j] = eq_b[col]; mnc[j] = mN[col];
  }
  float epr[2][4]; int mmr[2][4];
#pragma unroll
  for (int i = 0; i < 2; i++)
#pragma unroll
    for (int r = 0; r < 4; r++) {
      int row = m0 + wr + i * 16 + fq * 4 + r;
      epr[i][r] = ep_b[row]; mmr[i][r] = mM[row];
    }
  // UmT = masked(acc+ep); acc <- masked(acc+eq)
#pragma unroll
  for (int i = 0; i < 2; i++)
#pragma unroll
    for (int j = 0; j < 4; j++) {
      float4 tv;
#pragma unroll
      for (int r = 0; r < 4; r++) {
        float a = acc[i][j][r];
        bool ok = mmr[i][r] && mnc[j];
        ((float*)&tv)[r] = ok ? a + epr[i][r] : NEG_MAX;
        acc[i][j][r] = ok ? a + eqc[j] : NEG_MAX;
      }
      int col = wc + j * 16 + fr;
      *(float4*)(UmTB + (long)col * LP + m0 + wr + i * 16 + fq * 4) = tv;
    }
  // row max over 128 q: in-reg j, shfl over fr, LDS across the 2 n-waves
  float mx[2][4];
#pragma unroll
  for (int i = 0; i < 2; i++)
#pragma unroll
    for (int r = 0; r < 4; r++) {
      float m = fmaxf(fmaxf(acc[i][0][r], acc[i][1][r]), fmaxf(acc[i][2][r], acc[i][3][r]));
#pragma unroll
      for (int s = 1; s < 16; s <<= 1) m = fmaxf(m, __shfl_xor(m, s));
      mx[i][r] = m;
      if (fr == 0) smax[wn][wr + i * 16 + fq * 4 + r] = m;
    }
  __syncthreads();
#pragma unroll
  for (int i = 0; i < 2; i++)
#pragma unroll
    for (int r = 0; r < 4; r++) {
      int rl = wr + i * 16 + fq * 4 + r;
      mx[i][r] = fmaxf(smax[0][rl], smax[1][rl]);
    }
#pragma unroll
  for (int i = 0; i < 2; i++)
#pragma unroll
    for (int r = 0; r < 4; r++) {
      float s = 0.f;
#pragma unroll
      for (int j = 0; j < 4; j++) {
        float e = __expf(acc[i][j][r] - mx[i][r]);
        acc[i][j][r] = e; s += e;
      }
#pragma unroll
      for (int sh = 1; sh < 16; sh <<= 1) s += __shfl_xor(s, sh);
      if (fr == 0) ssum[wn][wr + i * 16 + fq * 4 + r] = s;
    }
  __syncthreads();
#pragma unroll
  for (int i = 0; i < 2; i++)
#pragma unroll
    for (int r = 0; r < 4; r++) {
      int rl = wr + i * 16 + fq * 4 + r;
      float S = ssum[0][rl] + ssum[1][rl];
      float inv = S > 0.f ? 1.f / S : 0.f;
      int row = m0 + rl;
#pragma unroll
      for (int j = 0; j < 4; j++) {
        int col = wc + j * 16 + fr;
        bool ok = mmr[i][r] && mnc[j];
        ApB[(long)row * LQ + col] = ok ? f2bf(acc[i][j][r] * inv) : 0;
      }
    }
}

// ---------------- col softmax over p (len 512) on UmT rows, wave per row -> BpT bf16 ----------------
__global__ __launch_bounds__(256) void colsoftmaxT_kernel(
    const float* __restrict__ UmT, unsigned short* __restrict__ BpT,
    const int* __restrict__ mp, const int* __restrict__ mq) {
  int wid = blockIdx.x * 4 + (threadIdx.x >> 6);  // = b*LQ + q
  int lane = threadIdx.x & 63;
  int b = wid >> 7;
  const float* row = UmT + (long)wid * LP;
  float v[8];
  float m = NEG_MAX;
#pragma unroll
  for (int i = 0; i < 8; i++) { v[i] = row[lane + 64 * i]; m = fmaxf(m, v[i]); }
#pragma unroll
  for (int off = 32; off; off >>= 1) m = fmaxf(m, __shfl_xor(m, off));
  float e[8];
  float s = 0.f;
#pragma unroll
  for (int i = 0; i < 8; i++) { e[i] = __expf(v[i] - m); s += e[i]; }
#pragma unroll
  for (int off = 32; off; off >>= 1) s += __shfl_xor(s, off);
  float inv = s > 0.f ? 1.f / s : 0.f;
  int mqv = mq[wid];
#pragma unroll
  for (int i = 0; i < 8; i++) {
    int p = lane + 64 * i;
    bool ok = mqv && mp[b * LP + p];
    BpT[(long)wid * LP + p] = ok ? f2bf(e[i] * inv) : 0;
  }
}

// ---------------- phase GEMMs ----------------
// grid (20, 1, 32). bx<4: "B-side" (M=128 q rows, A=BpT, K=512, B=BB[512h][512p]).
//                   bx>=4: "A-side" (M=512 p rows tiled by 128, A=Apb, K=128, B=BA[512h][128q]).
// PHASE=1: B-side={B1 -> gpq chunks 0,1,3 + B1T}, A-side={A1 -> gqp chunks 0,1,3 + A1T}.
// PHASE=2: B-side={B2 -> gpq chunks 2,4},        A-side={A2 -> gqp chunks 2,4}.
template <int PHASE>
__global__ __launch_bounds__(256) void gemm_phase(
    const unsigned short* __restrict__ Apb, const unsigned short* __restrict__ BpT,
    const unsigned short* __restrict__ BA, const unsigned short* __restrict__ BB,
    const unsigned short* __restrict__ Epb, const unsigned short* __restrict__ Eqb,
    const int* __restrict__ mp, const int* __restrict__ mq,
    float* __restrict__ out_gqp, float* __restrict__ out_gpq,
    unsigned short* __restrict__ A1T, unsigned short* __restrict__ B1T) {
  const int b = blockIdx.z, bx = blockIdx.x;
  __shared__ unsigned short As[8192], Bs[8192];
  const int t = threadIdx.x, lane = t & 63, wid = t >> 6;
  const int wr = (wid >> 1) * 64, wc = (wid & 1) * 64;
  const int fr = lane & 15, fq = lane >> 4;
  const unsigned short* A; const unsigned short* Bop;
  int K, M, m0, n0;
  float* outBase; const unsigned short* Eb; const int* mb;
  unsigned short* Tout;
  if (bx < 4) {  // B-side
    A = BpT + (long)b * LQ * LP; K = LP; M = LQ; m0 = 0; n0 = bx * 128;
    Bop = BB + (long)b * HDIM * LP;
    outBase = out_gpq + (long)b * LQ * GDIM;
    Eb = Eqb + (long)b * LQ * HDIM; mb = mq + (long)b * LQ;
    Tout = (PHASE == 1) ? B1T + (long)b * HDIM * LQ : nullptr;
  } else {       // A-side
    int idx = bx - 4; m0 = (idx >> 2) * 128; n0 = (idx & 3) * 128;
    A = Apb + (long)b * LP * LQ; K = LQ; M = LP;
    Bop = BA + (long)b * HDIM * LQ;
    outBase = out_gqp + (long)b * LP * GDIM;
    Eb = Epb + (long)b * LP * HDIM; mb = mp + (long)b * LP;
    Tout = (PHASE == 1) ? A1T + (long)b * HDIM * LP : nullptr;
  }
  f32x4 acc[4][4] = {};
  for (int k0 = 0; k0 < K; k0 += 64) {
    stage128x64(A, K, m0, k0, As, t);
    stage128x64(Bop, K, n0, k0, Bs, t);
    __syncthreads();
#pragma unroll
    for (int ks = 0; ks < 2; ks++) {
      short8 af[4], bfv[4];
#pragma unroll
      for (int i = 0; i < 4; i++) {
        af[i] = fragld(As, wr + i * 16 + fr, ks, fq);
        bfv[i] = fragld(Bs, wc + i * 16 + fr, ks, fq);
      }
#pragma unroll
      for (int i = 0; i < 4; i++)
#pragma unroll
        for (int j = 0; j < 4; j++)
          acc[i][j] = __builtin_amdgcn_mfma_f32_16x16x32_bf16(af[i], bfv[j], acc[i][j], 0, 0, 0);
    }
    __syncthreads();
  }
#pragma unroll
  for (int i = 0; i < 4; i++) {
#pragma unroll
    for (int r = 0; r < 4; r++) {
      int row = m0 + wr + i * 16 + fq * 4 + r;
      float mm = (float)mb[row];
      float* orow = outBase + (long)row * GDIM;
      const unsigned short* erow = Eb + (long)row * HDIM;
#pragma unroll
      for (int j = 0; j < 4; j++) {
        int col = n0 + wc + j * 16 + fr;
        float v = acc[i][j][r];
        float e = bf2f(erow[col]);
        if (PHASE == 1) {
          orow[col] = e * mm;
          orow[HDIM + col] = v * mm;
          orow[3 * HDIM + col] = e * v * mm;
        } else {
          orow[2 * HDIM + col] = v * mm;
          orow[4 * HDIM + col] = e * v * mm;
        }
      }
    }
    if (PHASE == 1) {
#pragma unroll
      for (int j = 0; j < 4; j++) {
        int col = n0 + wc + j * 16 + fr;
        int row0 = m0 + wr + i * 16 + fq * 4;
        ushort4v o = {f2bf(acc[i][j][0]), f2bf(acc[i][j][1]),
                      f2bf(acc[i][j][2]), f2bf(acc[i][j][3])};
        *(ushort4v*)(Tout + (long)col * M + row0) = o;
      }
    }
  }
}

extern "C" void kernel_launch(void* const* d_in, const int* in_sizes, int n_in,
                              void* d_out, int out_size, void* d_ws, size_t ws_size,
                              hipStream_t stream) {
  const float* Eq = (const float*)d_in[0];   // (32,128,512)
  const float* Ep = (const float*)d_in[1];   // (32,512,512)
  const int* mq = (const int*)d_in[2];       // (32,128)
  const int* mp = (const int*)d_in[3];       // (32,512)
  const float* w = (const float*)d_in[4];    // (1536,)
  float* out = (float*)d_out;
  float* out_gpq = out;                                  // (32,128,2560)
  float* out_gqp = out + (long)BBATCH * LQ * GDIM;       // (32,512,2560)

  unsigned short* Epb = (unsigned short*)d_ws;  // [32][512p][512h]
  unsigned short* EpT = Epb + 32L * 512 * 512;  // [32][512h][512p]
  unsigned short* Eqb = EpT + 32L * 512 * 512;  // [32][128q][512h]
  unsigned short* EqT = Eqb + 32L * 128 * 512;  // [32][512h][128q]
  unsigned short* Eqw = EqT + 32L * 512 * 128;  // [32][128q][512h] * wm
  unsigned short* Apb = Eqw + 32L * 128 * 512;  // [32][512p][128q]
  unsigned short* BpT = Apb + 32L * 512 * 128;  // [32][128q][512p]
  unsigned short* B1T = BpT + 32L * 128 * 512;  // [32][512h][128q]
  unsigned short* A1T = B1T + 32L * 512 * 128;  // [32][512h][512p]
  float* UmT = (float*)(A1T + 32L * 512 * 512); // [32][128q][512p]
  float* epb = UmT + 32L * 128 * 512;           // [32][512]
  float* eqb2 = epb + 32L * 512;                // [32][128]

  // 1. merged casts + exact f32 bias dots
  cast2_kernel<<<dim3(10, BBATCH), 256, 0, stream>>>(
      Ep, Eq, w, Epb, EpT, Eqb, EqT, Eqw, epb, eqb2);

  // 2. U GEMM (64-row tiles, 256 blocks) + fused row-softmax -> Apb, UmT
  u_gemm<<<dim3(1, 8, BBATCH), 256, 0, stream>>>(
      Epb, Eqw, epb, eqb2, mp, mq, UmT, Apb);

  // 3. col softmax -> BpT
  colsoftmaxT_kernel<<<BBATCH * LQ / 4, 256, 0, stream>>>(UmT, BpT, mp, mq);

  // 4. phase 1: B1 (gpq 0,1,3 + B1T) and A1 (gqp 0,1,3 + A1T)   [640 blocks]
  gemm_phase<1><<<dim3(20, 1, BBATCH), 256, 0, stream>>>(
      Apb, BpT, EqT, EpT, Epb, Eqb, mp, mq, out_gqp, out_gpq, A1T, B1T);

  // 5. phase 2: B2 = Bp^T@A1 (gpq 2,4) and A2 = Ap@B1 (gqp 2,4) [640 blocks]
  gemm_phase<2><<<dim3(20, 1, BBATCH), 256, 0, stream>>>(
      Apb, BpT, B1T, A1T, Epb, Eqb, mp, mq, out_gqp, out_gpq, nullptr, nullptr);
}

// Round 8
// 116.942 us; speedup vs baseline: 1.2865x; 1.1744x over previous
//
#include <hip/hip_runtime.h>
#include <hip/hip_bf16.h>

// Problem constants: B=8, NUM=4 -> BB=32 batches; LQ=128, LP=512, H=512.
#define BBATCH 32
#define LQ 128
#define LP 512
#define HDIM 512
#define GDIM 2560   // 5*H concat width
#define NEG_MAX (-3.402823466e38f)

typedef __attribute__((ext_vector_type(8))) short short8;
typedef __attribute__((ext_vector_type(4))) float f32x4;
typedef __attribute__((ext_vector_type(4))) unsigned short ushort4v;

__device__ inline unsigned short f2bf(float f) {
  union { float f; unsigned int u; } v; v.f = f;
  unsigned int r = v.u + 0x7FFFu + ((v.u >> 16) & 1u);  // RNE
  return (unsigned short)(r >> 16);
}
__device__ inline float bf2f(unsigned short s) {
  union { unsigned int u; float f; } v; v.u = (unsigned int)s << 16;
  return v.f;
}

// ---- staging / fragment helpers (rows x 64 k bf16 tiles, XOR-swizzled, 128B rows) ----
__device__ inline void stage128x64(const unsigned short* __restrict__ src, int ld,
                                   int row0, int k0, unsigned short* lds, int t) {
#pragma unroll
  for (int i = 0; i < 4; i++) {
    int o = (t + i * 256) * 16;
    int row = o >> 7, col = (o & 127) >> 1;
    int swz = o ^ ((row & 7) << 4);
    *(short8*)((char*)lds + swz) = *(const short8*)(src + (long)(row0 + row) * ld + k0 + col);
  }
}
__device__ inline void stage64x64(const unsigned short* __restrict__ src, int ld,
                                  int row0, int k0, unsigned short* lds, int t) {
#pragma unroll
  for (int i = 0; i < 2; i++) {
    int o = (t + i * 256) * 16;
    int row = o >> 7, col = (o & 127) >> 1;
    int swz = o ^ ((row & 7) << 4);
    *(short8*)((char*)lds + swz) = *(const short8*)(src + (long)(row0 + row) * ld + k0 + col);
  }
}
__device__ inline short8 fragld(const unsigned short* lds, int row, int ks, int fq) {
  return *(const short8*)((const char*)lds + (((row << 7) + ks * 64 + fq * 16) ^ ((row & 7) << 4)));
}

// ---------------- merged cast: Ep & Eq f32 -> bf16 {normal, transposed, (Eq: *wm)} + exact f32 bias dots ----------------
__global__ __launch_bounds__(256) void cast2_kernel(
    const float* __restrict__ Ep, const float* __restrict__ Eq,
    const float* __restrict__ w,
    unsigned short* __restrict__ Epb, unsigned short* __restrict__ EpT,
    unsigned short* __restrict__ Eqb, unsigned short* __restrict__ EqT,
    unsigned short* __restrict__ Eqw,
    float* __restrict__ epv, float* __restrict__ eqv) {
  const int b = blockIdx.y;
  const int bx = blockIdx.x;
  const bool isP = bx < 8;
  const int R = isP ? LP : LQ;
  const int p0 = (isP ? bx : bx - 8) * 64;
  const float* src = isP ? Ep + (long)b * LP * HDIM : Eq + (long)b * LQ * HDIM;
  const float* wb_base = isP ? w + HDIM : w;
  unsigned short* dN = isP ? Epb + (long)b * LP * HDIM : Eqb + (long)b * LQ * HDIM;
  unsigned short* dT = isP ? EpT + (long)b * HDIM * LP : EqT + (long)b * HDIM * LQ;
  unsigned short* dW = isP ? nullptr : Eqw + (long)b * LQ * HDIM;
  float* bias = (isP ? epv + b * LP : eqv + b * LQ) + p0;
  __shared__ float T[64][65];
  const int t = threadIdx.x, c4 = (t & 15) * 4, r = t >> 4;
  float dot[4] = {0.f, 0.f, 0.f, 0.f};
  for (int h0 = 0; h0 < HDIM; h0 += 64) {
    float4 wb = *(const float4*)(wb_base + h0 + c4);
    float4 wm4 = {0, 0, 0, 0};
    if (!isP) wm4 = *(const float4*)(w + 2 * HDIM + h0 + c4);
    __syncthreads();
#pragma unroll
    for (int i = 0; i < 4; i++) {
      int row = r + 16 * i;
      float4 v = *(const float4*)(src + (long)(p0 + row) * HDIM + h0 + c4);
      T[row][c4] = v.x; T[row][c4 + 1] = v.y; T[row][c4 + 2] = v.z; T[row][c4 + 3] = v.w;
      ushort4v o = {f2bf(v.x), f2bf(v.y), f2bf(v.z), f2bf(v.w)};
      *(ushort4v*)(dN + (long)(p0 + row) * HDIM + h0 + c4) = o;
      if (!isP) {
        ushort4v ow = {f2bf(v.x * wm4.x), f2bf(v.y * wm4.y), f2bf(v.z * wm4.z), f2bf(v.w * wm4.w)};
        *(ushort4v*)(dW + (long)(p0 + row) * HDIM + h0 + c4) = ow;
      }
      dot[i] += v.x * wb.x + v.y * wb.y + v.z * wb.z + v.w * wb.w;
    }
    __syncthreads();
#pragma unroll
    for (int i = 0; i < 4; i++) {
      int hh = r + 16 * i;
      ushort4v o = {f2bf(T[c4][hh]), f2bf(T[c4 + 1][hh]), f2bf(T[c4 + 2][hh]), f2bf(T[c4 + 3][hh])};
      *(ushort4v*)(dT + (long)(h0 + hh) * R + p0 + c4) = o;
    }
  }
#pragma unroll
  for (int i = 0; i < 4; i++) {
#pragma unroll
    for (int s = 1; s < 16; s <<= 1) dot[i] += __shfl_xor(dot[i], s);
  }
  if ((t & 15) == 0) {
#pragma unroll
    for (int i = 0; i < 4; i++) bias[r + 16 * i] = dot[i];
  }
}

// ---------------- U GEMM (64-row M-tile) + fused row-softmax ----------------
// grid: 256 blocks 1-D, XCD-swizzled. b = 4*xcd + s/8, m0 = (s%8)*64.
__global__ __launch_bounds__(256) void u_gemm(
    const unsigned short* __restrict__ Ab, const unsigned short* __restrict__ Bb,
    const float* __restrict__ epv, const float* __restrict__ eqv,
    const int* __restrict__ maskM, const int* __restrict__ maskN,
    float* __restrict__ UmT, unsigned short* __restrict__ Apb) {
  const int hw = blockIdx.x;
  const int xcd = hw & 7, s_ = hw >> 3;
  const int b = xcd * 4 + (s_ >> 3);
  const int m0 = (s_ & 7) * 64;
  const unsigned short* A = Ab + (long)b * LP * HDIM;
  const unsigned short* B = Bb + (long)b * LQ * HDIM;
  __shared__ unsigned short As[4096];  // 64 x 64
  __shared__ unsigned short Bs[8192];  // 128 x 64
  __shared__ float smax[2][64], ssum[2][64];
  const int t = threadIdx.x, lane = t & 63, wid = t >> 6;
  const int wm = wid >> 1, wn = wid & 1;
  const int wr = wm * 32, wc = wn * 64;
  const int fr = lane & 15, fq = lane >> 4;
  f32x4 acc[2][4] = {};
  for (int k0 = 0; k0 < HDIM; k0 += 64) {
    stage64x64(A, HDIM, m0, k0, As, t);
    stage128x64(B, HDIM, 0, k0, Bs, t);
    __syncthreads();
#pragma unroll
    for (int ks = 0; ks < 2; ks++) {
      short8 af[2], bfv[4];
#pragma unroll
      for (int i = 0; i < 2; i++) af[i] = fragld(As, wr + i * 16 + fr, ks, fq);
#pragma unroll
      for (int j = 0; j < 4; j++) bfv[j] = fragld(Bs, wc + j * 16 + fr, ks, fq);
#pragma unroll
      for (int i = 0; i < 2; i++)
#pragma unroll
        for (int j = 0; j < 4; j++)
          acc[i][j] = __builtin_amdgcn_mfma_f32_16x16x32_bf16(af[i], bfv[j], acc[i][j], 0, 0, 0);
    }
    __syncthreads();
  }
  const float* ep_b = epv + (long)b * LP;
  const float* eq_b = eqv + (long)b * LQ;
  const int* mM = maskM + (long)b * LP;
  const int* mN = maskN + (long)b * LQ;
  float* UmTB = UmT + (long)b * LQ * LP;        // [q][p]
  unsigned short* ApB = Apb + (long)b * LP * LQ; // [p][q]
  float eqc[4]; int mnc[4];
#pragma unroll
  for (int j = 0; j < 4; j++) {
    int col = wc + j * 16 + fr;
    eqc[j] = eq_b[col]; mnc[j] = mN[col];
  }
  float epr[2][4]; int mmr[2][4];
#pragma unroll
  for (int i = 0; i < 2; i++)
#pragma unroll
    for (int r = 0; r < 4; r++) {
      int row = m0 + wr + i * 16 + fq * 4 + r;
      epr[i][r] = ep_b[row]; mmr[i][r] = mM[row];
    }
  // UmT = masked(acc+ep); acc <- masked(acc+eq)
#pragma unroll
  for (int i = 0; i < 2; i++)
#pragma unroll
    for (int j = 0; j < 4; j++) {
      float4 tv;
#pragma unroll
      for (int r = 0; r < 4; r++) {
        float a = acc[i][j][r];
        bool ok = mmr[i][r] && mnc[j];
        ((float*)&tv)[r] = ok ? a + epr[i][r] : NEG_MAX;
        acc[i][j][r] = ok ? a + eqc[j] : NEG_MAX;
      }
      int col = wc + j * 16 + fr;
      *(float4*)(UmTB + (long)col * LP + m0 + wr + i * 16 + fq * 4) = tv;
    }
  float mx[2][4];
#pragma unroll
  for (int i = 0; i < 2; i++)
#pragma unroll
    for (int r = 0; r < 4; r++) {
      float m = fmaxf(fmaxf(acc[i][0][r], acc[i][1][r]), fmaxf(acc[i][2][r], acc[i][3][r]));
#pragma unroll
      for (int s = 1; s < 16; s <<= 1) m = fmaxf(m, __shfl_xor(m, s));
      mx[i][r] = m;
      if (fr == 0) smax[wn][wr + i * 16 + fq * 4 + r] = m;
    }
  __syncthreads();
#pragma unroll
  for (int i = 0; i < 2; i++)
#pragma unroll
    for (int r = 0; r < 4; r++) {
      int rl = wr + i * 16 + fq * 4 + r;
      mx[i][r] = fmaxf(smax[0][rl], smax[1][rl]);
    }
#pragma unroll
  for (int i = 0; i < 2; i++)
#pragma unroll
    for (int r = 0; r < 4; r++) {
      float s = 0.f;
#pragma unroll
      for (int j = 0; j < 4; j++) {
        float e = __expf(acc[i][j][r] - mx[i][r]);
        acc[i][j][r] = e; s += e;
      }
#pragma unroll
      for (int sh = 1; sh < 16; sh <<= 1) s += __shfl_xor(s, sh);
      if (fr == 0) ssum[wn][wr + i * 16 + fq * 4 + r] = s;
    }
  __syncthreads();
#pragma unroll
  for (int i = 0; i < 2; i++)
#pragma unroll
    for (int r = 0; r < 4; r++) {
      int rl = wr + i * 16 + fq * 4 + r;
      float S = ssum[0][rl] + ssum[1][rl];
      float inv = S > 0.f ? 1.f / S : 0.f;
      int row = m0 + rl;
#pragma unroll
      for (int j = 0; j < 4; j++) {
        int col = wc + j * 16 + fr;
        bool ok = mmr[i][r] && mnc[j];
        ApB[(long)row * LQ + col] = ok ? f2bf(acc[i][j][r] * inv) : 0;
      }
    }
}

// ---------------- col softmax over p (len 512) on UmT rows, wave per row -> BpT bf16 ----------------
__global__ __launch_bounds__(256) void colsoftmaxT_kernel(
    const float* __restrict__ UmT, unsigned short* __restrict__ BpT,
    const int* __restrict__ mp, const int* __restrict__ mq) {
  int wid = blockIdx.x * 4 + (threadIdx.x >> 6);  // = b*LQ + q
  int lane = threadIdx.x & 63;
  int b = wid >> 7;
  const float* row = UmT + (long)wid * LP;
  float v[8];
  float m = NEG_MAX;
#pragma unroll
  for (int i = 0; i < 8; i++) { v[i] = row[lane + 64 * i]; m = fmaxf(m, v[i]); }
#pragma unroll
  for (int off = 32; off; off >>= 1) m = fmaxf(m, __shfl_xor(m, off));
  float e[8];
  float s = 0.f;
#pragma unroll
  for (int i = 0; i < 8; i++) { e[i] = __expf(v[i] - m); s += e[i]; }
#pragma unroll
  for (int off = 32; off; off >>= 1) s += __shfl_xor(s, off);
  float inv = s > 0.f ? 1.f / s : 0.f;
  int mqv = mq[wid];
#pragma unroll
  for (int i = 0; i < 8; i++) {
    int p = lane + 64 * i;
    bool ok = mqv && mp[b * LP + p];
    BpT[(long)wid * LP + p] = ok ? f2bf(e[i] * inv) : 0;
  }
}

// ---------------- phase GEMMs ----------------
// grid: 640 blocks 1-D, XCD-swizzled: xcd = hw&7, s = hw>>3, b = 4*xcd + s/20, tile = s%20.
// tile<4: "B-side" (M=128 q rows, A=BpT, K=512, B=BB[512h][512p]).
// tile>=4: "A-side" (M=512 p rows tiled by 128, A=Apb, K=128, B=BA[512h][128q]).
// PHASE=1: B-side={B1 -> gpq chunks 0,1,3 + B1T}, A-side={A1 -> gqp chunks 0,1,3 + A1T}.
// PHASE=2: B-side={B2 -> gpq chunks 2,4},        A-side={A2 -> gqp chunks 2,4}.
template <int PHASE>
__global__ __launch_bounds__(256) void gemm_phase(
    const unsigned short* __restrict__ Apb, const unsigned short* __restrict__ BpT,
    const unsigned short* __restrict__ BA, const unsigned short* __restrict__ BB,
    const unsigned short* __restrict__ Epb, const unsigned short* __restrict__ Eqb,
    const int* __restrict__ mp, const int* __restrict__ mq,
    float* __restrict__ out_gqp, float* __restrict__ out_gpq,
    unsigned short* __restrict__ A1T, unsigned short* __restrict__ B1T) {
  const int hw = blockIdx.x;
  const int xcd = hw & 7, s_ = hw >> 3;
  const int b = xcd * 4 + (s_ / 20);
  const int bx = s_ % 20;
  __shared__ unsigned short As[8192], Bs[8192];
  const int t = threadIdx.x, lane = t & 63, wid = t >> 6;
  const int wr = (wid >> 1) * 64, wc = (wid & 1) * 64;
  const int fr = lane & 15, fq = lane >> 4;
  const unsigned short* A; const unsigned short* Bop;
  int K, M, m0, n0;
  float* outBase; const unsigned short* Eb; const int* mb;
  unsigned short* Tout;
  if (bx < 4) {  // B-side
    A = BpT + (long)b * LQ * LP; K = LP; M = LQ; m0 = 0; n0 = bx * 128;
    Bop = BB + (long)b * HDIM * LP;
    outBase = out_gpq + (long)b * LQ * GDIM;
    Eb = Eqb + (long)b * LQ * HDIM; mb = mq + (long)b * LQ;
    Tout = (PHASE == 1) ? B1T + (long)b * HDIM * LQ : nullptr;
  } else {       // A-side
    int idx = bx - 4; m0 = (idx >> 2) * 128; n0 = (idx & 3) * 128;
    A = Apb + (long)b * LP * LQ; K = LQ; M = LP;
    Bop = BA + (long)b * HDIM * LQ;
    outBase = out_gqp + (long)b * LP * GDIM;
    Eb = Epb + (long)b * LP * HDIM; mb = mp + (long)b * LP;
    Tout = (PHASE == 1) ? A1T + (long)b * HDIM * LP : nullptr;
  }
  f32x4 acc[4][4] = {};
  for (int k0 = 0; k0 < K; k0 += 64) {
    stage128x64(A, K, m0, k0, As, t);
    stage128x64(Bop, K, n0, k0, Bs, t);
    __syncthreads();
#pragma unroll
    for (int ks = 0; ks < 2; ks++) {
      short8 af[4], bfv[4];
#pragma unroll
      for (int i = 0; i < 4; i++) {
        af[i] = fragld(As, wr + i * 16 + fr, ks, fq);
        bfv[i] = fragld(Bs, wc + i * 16 + fr, ks, fq);
      }
#pragma unroll
      for (int i = 0; i < 4; i++)
#pragma unroll
        for (int j = 0; j < 4; j++)
          acc[i][j] = __builtin_amdgcn_mfma_f32_16x16x32_bf16(af[i], bfv[j], acc[i][j], 0, 0, 0);
    }
    __syncthreads();
  }
#pragma unroll
  for (int i = 0; i < 4; i++) {
#pragma unroll
    for (int r = 0; r < 4; r++) {
      int row = m0 + wr + i * 16 + fq * 4 + r;
      float mm = (float)mb[row];
      float* orow = outBase + (long)row * GDIM;
      const unsigned short* erow = Eb + (long)row * HDIM;
#pragma unroll
      for (int j = 0; j < 4; j++) {
        int col = n0 + wc + j * 16 + fr;
        float v = acc[i][j][r];
        float e = bf2f(erow[col]);
        if (PHASE == 1) {
          __builtin_nontemporal_store(e * mm, orow + col);
          __builtin_nontemporal_store(v * mm, orow + HDIM + col);
          __builtin_nontemporal_store(e * v * mm, orow + 3 * HDIM + col);
        } else {
          __builtin_nontemporal_store(v * mm, orow + 2 * HDIM + col);
          __builtin_nontemporal_store(e * v * mm, orow + 4 * HDIM + col);
        }
      }
    }
    if (PHASE == 1) {
#pragma unroll
      for (int j = 0; j < 4; j++) {
        int col = n0 + wc + j * 16 + fr;
        int row0 = m0 + wr + i * 16 + fq * 4;
        ushort4v o = {f2bf(acc[i][j][0]), f2bf(acc[i][j][1]),
                      f2bf(acc[i][j][2]), f2bf(acc[i][j][3])};
        *(ushort4v*)(Tout + (long)col * M + row0) = o;
      }
    }
  }
}

extern "C" void kernel_launch(void* const* d_in, const int* in_sizes, int n_in,
                              void* d_out, int out_size, void* d_ws, size_t ws_size,
                              hipStream_t stream) {
  const float* Eq = (const float*)d_in[0];   // (32,128,512)
  const float* Ep = (const float*)d_in[1];   // (32,512,512)
  const int* mq = (const int*)d_in[2];       // (32,128)
  const int* mp = (const int*)d_in[3];       // (32,512)
  const float* w = (const float*)d_in[4];    // (1536,)
  float* out = (float*)d_out;
  float* out_gpq = out;                                  // (32,128,2560)
  float* out_gqp = out + (long)BBATCH * LQ * GDIM;       // (32,512,2560)

  unsigned short* Epb = (unsigned short*)d_ws;  // [32][512p][512h]
  unsigned short* EpT = Epb + 32L * 512 * 512;  // [32][512h][512p]
  unsigned short* Eqb = EpT + 32L * 512 * 512;  // [32][128q][512h]
  unsigned short* EqT = Eqb + 32L * 128 * 512;  // [32][512h][128q]
  unsigned short* Eqw = EqT + 32L * 512 * 128;  // [32][128q][512h] * wm
  unsigned short* Apb = Eqw + 32L * 128 * 512;  // [32][512p][128q]
  unsigned short* BpT = Apb + 32L * 512 * 128;  // [32][128q][512p]
  unsigned short* B1T = BpT + 32L * 128 * 512;  // [32][512h][128q]
  unsigned short* A1T = B1T + 32L * 512 * 128;  // [32][512h][512p]
  float* UmT = (float*)(A1T + 32L * 512 * 512); // [32][128q][512p]
  float* epb = UmT + 32L * 128 * 512;           // [32][512]
  float* eqb2 = epb + 32L * 512;                // [32][128]

  // 1. merged casts + exact f32 bias dots
  cast2_kernel<<<dim3(10, BBATCH), 256, 0, stream>>>(
      Ep, Eq, w, Epb, EpT, Eqb, EqT, Eqw, epb, eqb2);

  // 2. U GEMM (64-row tiles, 256 blocks, XCD-swizzled) + fused row-softmax -> Apb, UmT
  u_gemm<<<dim3(256), 256, 0, stream>>>(
      Epb, Eqw, epb, eqb2, mp, mq, UmT, Apb);

  // 3. col softmax -> BpT
  colsoftmaxT_kernel<<<BBATCH * LQ / 4, 256, 0, stream>>>(UmT, BpT, mp, mq);

  // 4. phase 1: B1 (gpq 0,1,3 + B1T) and A1 (gqp 0,1,3 + A1T)   [640 blocks, XCD-swizzled]
  gemm_phase<1><<<dim3(640), 256, 0, stream>>>(
      Apb, BpT, EqT, EpT, Epb, Eqb, mp, mq, out_gqp, out_gpq, A1T, B1T);

  // 5. phase 2: B2 = Bp^T@A1 (gpq 2,4) and A2 = Ap@B1 (gqp 2,4) [640 blocks, XCD-swizzled]
  gemm_phase<2><<<dim3(640), 256, 0, stream>>>(
      Apb, BpT, B1T, A1T, Epb, Eqb, mp, mq, out_gqp, out_gpq, nullptr, nullptr);
}

// Round 9
// 107.225 us; speedup vs baseline: 1.4031x; 1.0906x over previous
//
#include <hip/hip_runtime.h>
#include <hip/hip_bf16.h>

// Problem constants: B=8, NUM=4 -> BB=32 batches; LQ=128, LP=512, H=512.
#define BBATCH 32
#define LQ 128
#define LP 512
#define HDIM 512
#define GDIM 2560   // 5*H concat width
#define NEG_MAX (-3.402823466e38f)

typedef __attribute__((ext_vector_type(8))) short short8;
typedef __attribute__((ext_vector_type(4))) float f32x4;
typedef __attribute__((ext_vector_type(4))) unsigned short ushort4v;

__device__ inline unsigned short f2bf(float f) {
  union { float f; unsigned int u; } v; v.f = f;
  unsigned int r = v.u + 0x7FFFu + ((v.u >> 16) & 1u);  // RNE
  return (unsigned short)(r >> 16);
}
__device__ inline float bf2f(unsigned short s) {
  union { unsigned int u; float f; } v; v.u = (unsigned int)s << 16;
  return v.f;
}

// ---- staging / fragment helpers (rows x 64 k bf16 tiles, XOR-swizzled, 128B rows) ----
__device__ inline void stage128x64(const unsigned short* __restrict__ src, int ld,
                                   int row0, int k0, unsigned short* lds, int t) {
#pragma unroll
  for (int i = 0; i < 4; i++) {
    int o = (t + i * 256) * 16;
    int row = o >> 7, col = (o & 127) >> 1;
    int swz = o ^ ((row & 7) << 4);
    *(short8*)((char*)lds + swz) = *(const short8*)(src + (long)(row0 + row) * ld + k0 + col);
  }
}
// f32 source -> bf16 LDS (convert in-register; identical bits to pre-cast path)
__device__ inline void stage64x64_f32(const float* __restrict__ src, int ld,
                                      int row0, int k0, unsigned short* lds, int t) {
#pragma unroll
  for (int i = 0; i < 2; i++) {
    int o = (t + i * 256) * 16;
    int row = o >> 7, col = (o & 127) >> 1;
    int swz = o ^ ((row & 7) << 4);
    const float* p = src + (long)(row0 + row) * ld + k0 + col;
    float4 a = *(const float4*)p;
    float4 b2 = *(const float4*)(p + 4);
    short8 v = {(short)f2bf(a.x), (short)f2bf(a.y), (short)f2bf(a.z), (short)f2bf(a.w),
                (short)f2bf(b2.x), (short)f2bf(b2.y), (short)f2bf(b2.z), (short)f2bf(b2.w)};
    *(short8*)((char*)lds + swz) = v;
  }
}
__device__ inline short8 fragld(const unsigned short* lds, int row, int ks, int fq) {
  return *(const short8*)((const char*)lds + (((row << 7) + ks * 64 + fq * 16) ^ ((row & 7) << 4)));
}

// ---------------- prep: Ep & Eq f32 -> bf16 transposed (+ Eqw) + exact f32 bias dots ----------------
__global__ __launch_bounds__(256) void prep_kernel(
    const float* __restrict__ Ep, const float* __restrict__ Eq,
    const float* __restrict__ w,
    unsigned short* __restrict__ EpT, unsigned short* __restrict__ EqT,
    unsigned short* __restrict__ Eqw,
    float* __restrict__ epv, float* __restrict__ eqv) {
  const int b = blockIdx.y;
  const int bx = blockIdx.x;
  const bool isP = bx < 8;
  const int R = isP ? LP : LQ;
  const int p0 = (isP ? bx : bx - 8) * 64;
  const float* src = isP ? Ep + (long)b * LP * HDIM : Eq + (long)b * LQ * HDIM;
  const float* wb_base = isP ? w + HDIM : w;
  unsigned short* dT = isP ? EpT + (long)b * HDIM * LP : EqT + (long)b * HDIM * LQ;
  unsigned short* dW = isP ? nullptr : Eqw + (long)b * LQ * HDIM;
  float* bias = (isP ? epv + b * LP : eqv + b * LQ) + p0;
  __shared__ float T[64][65];
  const int t = threadIdx.x, c4 = (t & 15) * 4, r = t >> 4;
  float dot[4] = {0.f, 0.f, 0.f, 0.f};
  for (int h0 = 0; h0 < HDIM; h0 += 64) {
    float4 wb = *(const float4*)(wb_base + h0 + c4);
    float4 wm4 = {0, 0, 0, 0};
    if (!isP) wm4 = *(const float4*)(w + 2 * HDIM + h0 + c4);
    __syncthreads();
#pragma unroll
    for (int i = 0; i < 4; i++) {
      int row = r + 16 * i;
      float4 v = *(const float4*)(src + (long)(p0 + row) * HDIM + h0 + c4);
      T[row][c4] = v.x; T[row][c4 + 1] = v.y; T[row][c4 + 2] = v.z; T[row][c4 + 3] = v.w;
      if (!isP) {
        ushort4v ow = {f2bf(v.x * wm4.x), f2bf(v.y * wm4.y), f2bf(v.z * wm4.z), f2bf(v.w * wm4.w)};
        *(ushort4v*)(dW + (long)(p0 + row) * HDIM + h0 + c4) = ow;
      }
      dot[i] += v.x * wb.x + v.y * wb.y + v.z * wb.z + v.w * wb.w;
    }
    __syncthreads();
#pragma unroll
    for (int i = 0; i < 4; i++) {
      int hh = r + 16 * i;
      ushort4v o = {f2bf(T[c4][hh]), f2bf(T[c4 + 1][hh]), f2bf(T[c4 + 2][hh]), f2bf(T[c4 + 3][hh])};
      *(ushort4v*)(dT + (long)(h0 + hh) * R + p0 + c4) = o;
    }
  }
#pragma unroll
  for (int i = 0; i < 4; i++) {
#pragma unroll
    for (int s = 1; s < 16; s <<= 1) dot[i] += __shfl_xor(dot[i], s);
  }
  if ((t & 15) == 0) {
#pragma unroll
    for (int i = 0; i < 4; i++) bias[r + 16 * i] = dot[i];
  }
}

// ---------------- U GEMM (64-row M-tile) + fused row-softmax ----------------
// grid: 256 blocks 1-D, XCD-swizzled. A staged from f32 Ep; B = Eqw bf16.
__global__ __launch_bounds__(256) void u_gemm(
    const float* __restrict__ EpF, const unsigned short* __restrict__ Bb,
    const float* __restrict__ epv, const float* __restrict__ eqv,
    const int* __restrict__ maskM, const int* __restrict__ maskN,
    float* __restrict__ UmT, unsigned short* __restrict__ Apb) {
  const int hw = blockIdx.x;
  const int xcd = hw & 7, s_ = hw >> 3;
  const int b = xcd * 4 + (s_ >> 3);
  const int m0 = (s_ & 7) * 64;
  const float* A = EpF + (long)b * LP * HDIM;
  const unsigned short* B = Bb + (long)b * LQ * HDIM;
  __shared__ unsigned short As[4096];  // 64 x 64
  __shared__ unsigned short Bs[8192];  // 128 x 64
  __shared__ float smax[2][64], ssum[2][64];
  const int t = threadIdx.x, lane = t & 63, wid = t >> 6;
  const int wm = wid >> 1, wn = wid & 1;
  const int wr = wm * 32, wc = wn * 64;
  const int fr = lane & 15, fq = lane >> 4;
  f32x4 acc[2][4] = {};
  for (int k0 = 0; k0 < HDIM; k0 += 64) {
    stage64x64_f32(A, HDIM, m0, k0, As, t);
    stage128x64(B, HDIM, 0, k0, Bs, t);
    __syncthreads();
#pragma unroll
    for (int ks = 0; ks < 2; ks++) {
      short8 af[2], bfv[4];
#pragma unroll
      for (int i = 0; i < 2; i++) af[i] = fragld(As, wr + i * 16 + fr, ks, fq);
#pragma unroll
      for (int j = 0; j < 4; j++) bfv[j] = fragld(Bs, wc + j * 16 + fr, ks, fq);
#pragma unroll
      for (int i = 0; i < 2; i++)
#pragma unroll
        for (int j = 0; j < 4; j++)
          acc[i][j] = __builtin_amdgcn_mfma_f32_16x16x32_bf16(af[i], bfv[j], acc[i][j], 0, 0, 0);
    }
    __syncthreads();
  }
  const float* ep_b = epv + (long)b * LP;
  const float* eq_b = eqv + (long)b * LQ;
  const int* mM = maskM + (long)b * LP;
  const int* mN = maskN + (long)b * LQ;
  float* UmTB = UmT + (long)b * LQ * LP;        // [q][p]
  unsigned short* ApB = Apb + (long)b * LP * LQ; // [p][q]
  float eqc[4]; int mnc[4];
#pragma unroll
  for (int j = 0; j < 4; j++) {
    int col = wc + j * 16 + fr;
    eqc[j] = eq_b[col]; mnc[j] = mN[col];
  }
  float epr[2][4]; int mmr[2][4];
#pragma unroll
  for (int i = 0; i < 2; i++)
#pragma unroll
    for (int r = 0; r < 4; r++) {
      int row = m0 + wr + i * 16 + fq * 4 + r;
      epr[i][r] = ep_b[row]; mmr[i][r] = mM[row];
    }
#pragma unroll
  for (int i = 0; i < 2; i++)
#pragma unroll
    for (int j = 0; j < 4; j++) {
      float4 tv;
#pragma unroll
      for (int r = 0; r < 4; r++) {
        float a = acc[i][j][r];
        bool ok = mmr[i][r] && mnc[j];
        ((float*)&tv)[r] = ok ? a + epr[i][r] : NEG_MAX;
        acc[i][j][r] = ok ? a + eqc[j] : NEG_MAX;
      }
      int col = wc + j * 16 + fr;
      *(float4*)(UmTB + (long)col * LP + m0 + wr + i * 16 + fq * 4) = tv;
    }
  float mx[2][4];
#pragma unroll
  for (int i = 0; i < 2; i++)
#pragma unroll
    for (int r = 0; r < 4; r++) {
      float m = fmaxf(fmaxf(acc[i][0][r], acc[i][1][r]), fmaxf(acc[i][2][r], acc[i][3][r]));
#pragma unroll
      for (int s = 1; s < 16; s <<= 1) m = fmaxf(m, __shfl_xor(m, s));
      mx[i][r] = m;
      if (fr == 0) smax[wn][wr + i * 16 + fq * 4 + r] = m;
    }
  __syncthreads();
#pragma unroll
  for (int i = 0; i < 2; i++)
#pragma unroll
    for (int r = 0; r < 4; r++) {
      int rl = wr + i * 16 + fq * 4 + r;
      mx[i][r] = fmaxf(smax[0][rl], smax[1][rl]);
    }
#pragma unroll
  for (int i = 0; i < 2; i++)
#pragma unroll
    for (int r = 0; r < 4; r++) {
      float s = 0.f;
#pragma unroll
      for (int j = 0; j < 4; j++) {
        float e = __expf(acc[i][j][r] - mx[i][r]);
        acc[i][j][r] = e; s += e;
      }
#pragma unroll
      for (int sh = 1; sh < 16; sh <<= 1) s += __shfl_xor(s, sh);
      if (fr == 0) ssum[wn][wr + i * 16 + fq * 4 + r] = s;
    }
  __syncthreads();
#pragma unroll
  for (int i = 0; i < 2; i++)
#pragma unroll
    for (int r = 0; r < 4; r++) {
      int rl = wr + i * 16 + fq * 4 + r;
      float S = ssum[0][rl] + ssum[1][rl];
      float inv = S > 0.f ? 1.f / S : 0.f;
      int row = m0 + rl;
#pragma unroll
      for (int j = 0; j < 4; j++) {
        int col = wc + j * 16 + fr;
        bool ok = mmr[i][r] && mnc[j];
        ApB[(long)row * LQ + col] = ok ? f2bf(acc[i][j][r] * inv) : 0;
      }
    }
}

// ---------------- col softmax over p (len 512) on UmT rows, wave per row -> BpT bf16 ----------------
__global__ __launch_bounds__(256) void colsoftmaxT_kernel(
    const float* __restrict__ UmT, unsigned short* __restrict__ BpT,
    const int* __restrict__ mp, const int* __restrict__ mq) {
  int wid = blockIdx.x * 4 + (threadIdx.x >> 6);  // = b*LQ + q
  int lane = threadIdx.x & 63;
  int b = wid >> 7;
  const float* row = UmT + (long)wid * LP;
  float v[8];
  float m = NEG_MAX;
#pragma unroll
  for (int i = 0; i < 8; i++) { v[i] = row[lane + 64 * i]; m = fmaxf(m, v[i]); }
#pragma unroll
  for (int off = 32; off; off >>= 1) m = fmaxf(m, __shfl_xor(m, off));
  float e[8];
  float s = 0.f;
#pragma unroll
  for (int i = 0; i < 8; i++) { e[i] = __expf(v[i] - m); s += e[i]; }
#pragma unroll
  for (int off = 32; off; off >>= 1) s += __shfl_xor(s, off);
  float inv = s > 0.f ? 1.f / s : 0.f;
  int mqv = mq[wid];
#pragma unroll
  for (int i = 0; i < 8; i++) {
    int p = lane + 64 * i;
    bool ok = mqv && mp[b * LP + p];
    BpT[(long)wid * LP + p] = ok ? f2bf(e[i] * inv) : 0;
  }
}

// ---------------- phase GEMMs ----------------
// grid: 640 blocks 1-D, XCD-swizzled. tile<4: B-side (M=128q, K=512); else A-side (M=512p, K=128).
// Epilogue: acc slices staged via LDS -> float4 nt stores; E read as f32 float4.
template <int PHASE>
__global__ __launch_bounds__(256) void gemm_phase(
    const unsigned short* __restrict__ Apb, const unsigned short* __restrict__ BpT,
    const unsigned short* __restrict__ BA, const unsigned short* __restrict__ BB,
    const float* __restrict__ EpF, const float* __restrict__ EqF,
    const int* __restrict__ mp, const int* __restrict__ mq,
    float* __restrict__ out_gqp, float* __restrict__ out_gpq,
    unsigned short* __restrict__ A1T, unsigned short* __restrict__ B1T) {
  const int hw = blockIdx.x;
  const int xcd = hw & 7, s_ = hw >> 3;
  const int b = xcd * 4 + (s_ / 20);
  const int bx = s_ % 20;
  __shared__ __align__(16) char smem[32768];
  unsigned short* As = (unsigned short*)smem;
  unsigned short* Bs = (unsigned short*)(smem + 16384);
  float (*Cs)[132] = (float(*)[132])smem;  // aliases As/Bs after K-loop
  const int t = threadIdx.x, lane = t & 63, wid = t >> 6;
  const int wr = (wid >> 1) * 64, wc = (wid & 1) * 64;
  const int fr = lane & 15, fq = lane >> 4;
  const unsigned short* A; const unsigned short* Bop;
  int K, M, m0, n0;
  float* outBase; const float* Eb; const int* mb;
  unsigned short* Tout;
  if (bx < 4) {  // B-side
    A = BpT + (long)b * LQ * LP; K = LP; M = LQ; m0 = 0; n0 = bx * 128;
    Bop = BB + (long)b * HDIM * LP;
    outBase = out_gpq + (long)b * LQ * GDIM;
    Eb = EqF + (long)b * LQ * HDIM; mb = mq + (long)b * LQ;
    Tout = (PHASE == 1) ? B1T + (long)b * HDIM * LQ : nullptr;
  } else {       // A-side
    int idx = bx - 4; m0 = (idx >> 2) * 128; n0 = (idx & 3) * 128;
    A = Apb + (long)b * LP * LQ; K = LQ; M = LP;
    Bop = BA + (long)b * HDIM * LQ;
    outBase = out_gqp + (long)b * LP * GDIM;
    Eb = EpF + (long)b * LP * HDIM; mb = mp + (long)b * LP;
    Tout = (PHASE == 1) ? A1T + (long)b * HDIM * LP : nullptr;
  }
  f32x4 acc[4][4] = {};
  for (int k0 = 0; k0 < K; k0 += 64) {
    stage128x64(A, K, m0, k0, As, t);
    stage128x64(Bop, K, n0, k0, Bs, t);
    __syncthreads();
#pragma unroll
    for (int ks = 0; ks < 2; ks++) {
      short8 af[4], bfv[4];
#pragma unroll
      for (int i = 0; i < 4; i++) {
        af[i] = fragld(As, wr + i * 16 + fr, ks, fq);
        bfv[i] = fragld(Bs, wc + i * 16 + fr, ks, fq);
      }
#pragma unroll
      for (int i = 0; i < 4; i++)
#pragma unroll
        for (int j = 0; j < 4; j++)
          acc[i][j] = __builtin_amdgcn_mfma_f32_16x16x32_bf16(af[i], bfv[j], acc[i][j], 0, 0, 0);
    }
    __syncthreads();
  }
  // ---- Tout (A1T/B1T) bf16 transposed writes (from regs) ----
  if (PHASE == 1) {
#pragma unroll
    for (int i = 0; i < 4; i++)
#pragma unroll
      for (int j = 0; j < 4; j++) {
        int col = n0 + wc + j * 16 + fr;
        int row0 = m0 + wr + i * 16 + fq * 4;
        ushort4v o = {f2bf(acc[i][j][0]), f2bf(acc[i][j][1]),
                      f2bf(acc[i][j][2]), f2bf(acc[i][j][3])};
        *(ushort4v*)(Tout + (long)col * M + row0) = o;
      }
  }
  // ---- 5-chunk output: LDS-vectorized, float4 nt stores + f32 E float4 loads ----
  const int band = wid >> 1;
#pragma unroll
  for (int i = 0; i < 4; i++) {
    __syncthreads();  // previous slice reads done (and K-loop LDS reads for i=0)
#pragma unroll
    for (int j = 0; j < 4; j++) {
#pragma unroll
      for (int r = 0; r < 4; r++)
        Cs[band * 16 + fq * 4 + r][wc + j * 16 + fr] = acc[i][j][r];
    }
    __syncthreads();
#pragma unroll
    for (int k = 0; k < 4; k++) {
      int slot = t + k * 256;          // 0..1023
      int row_l = slot >> 5;           // 0..31
      int c4 = (slot & 31) * 4;        // 0..124
      int bnd = row_l >> 4;
      int r_g = m0 + bnd * 64 + i * 16 + (row_l & 15);
      float mm = (float)mb[r_g];
      f32x4 v = *(f32x4*)&Cs[row_l][c4];
      f32x4 e = *(const f32x4*)(Eb + (long)r_g * HDIM + n0 + c4);
      float* orow = outBase + (long)r_g * GDIM + n0 + c4;
      f32x4 vm = v * mm;
      f32x4 evm = e * vm;
      if (PHASE == 1) {
        __builtin_nontemporal_store(e * mm, (f32x4*)(orow));
        __builtin_nontemporal_store(vm, (f32x4*)(orow + HDIM));
        __builtin_nontemporal_store(evm, (f32x4*)(orow + 3 * HDIM));
      } else {
        __builtin_nontemporal_store(vm, (f32x4*)(orow + 2 * HDIM));
        __builtin_nontemporal_store(evm, (f32x4*)(orow + 4 * HDIM));
      }
    }
  }
}

extern "C" void kernel_launch(void* const* d_in, const int* in_sizes, int n_in,
                              void* d_out, int out_size, void* d_ws, size_t ws_size,
                              hipStream_t stream) {
  const float* Eq = (const float*)d_in[0];   // (32,128,512)
  const float* Ep = (const float*)d_in[1];   // (32,512,512)
  const int* mq = (const int*)d_in[2];       // (32,128)
  const int* mp = (const int*)d_in[3];       // (32,512)
  const float* w = (const float*)d_in[4];    // (1536,)
  float* out = (float*)d_out;
  float* out_gpq = out;                                  // (32,128,2560)
  float* out_gqp = out + (long)BBATCH * LQ * GDIM;       // (32,512,2560)

  unsigned short* EpT = (unsigned short*)d_ws;  // [32][512h][512p]
  unsigned short* EqT = EpT + 32L * 512 * 512;  // [32][512h][128q]
  unsigned short* Eqw = EqT + 32L * 512 * 128;  // [32][128q][512h] * wm
  unsigned short* Apb = Eqw + 32L * 128 * 512;  // [32][512p][128q]
  unsigned short* BpT = Apb + 32L * 512 * 128;  // [32][128q][512p]
  unsigned short* B1T = BpT + 32L * 128 * 512;  // [32][512h][128q]
  unsigned short* A1T = B1T + 32L * 512 * 128;  // [32][512h][512p]
  float* UmT = (float*)(A1T + 32L * 512 * 512); // [32][128q][512p]
  float* epb = UmT + 32L * 128 * 512;           // [32][512]
  float* eqb2 = epb + 32L * 512;                // [32][128]

  // 1. prep: transposes + Eqw + exact f32 bias dots
  prep_kernel<<<dim3(10, BBATCH), 256, 0, stream>>>(
      Ep, Eq, w, EpT, EqT, Eqw, epb, eqb2);

  // 2. U GEMM (A from f32 Ep) + fused row-softmax -> Apb, UmT
  u_gemm<<<dim3(256), 256, 0, stream>>>(
      Ep, Eqw, epb, eqb2, mp, mq, UmT, Apb);

  // 3. col softmax -> BpT
  colsoftmaxT_kernel<<<BBATCH * LQ / 4, 256, 0, stream>>>(UmT, BpT, mp, mq);

  // 4. phase 1: B1 (gpq 0,1,3 + B1T) and A1 (gqp 0,1,3 + A1T)   [640 blocks]
  gemm_phase<1><<<dim3(640), 256, 0, stream>>>(
      Apb, BpT, EqT, EpT, Ep, Eq, mp, mq, out_gqp, out_gpq, A1T, B1T);

  // 5. phase 2: B2 = Bp^T@A1 (gpq 2,4) and A2 = Ap@B1 (gqp 2,4) [640 blocks]
  gemm_phase<2><<<dim3(640), 256, 0, stream>>>(
      Apb, BpT, B1T, A1T, Ep, Eq, mp, mq, out_gqp, out_gpq, nullptr, nullptr);
}